// Round 3
// baseline (818.655 us; speedup 1.0000x reference)
//
#include <hip/hip_runtime.h>
#include <math.h>

typedef unsigned long long u64;

#define BN 8
#define NA_T 9
#define NPOS 2500
#define FHW 50
#define N_ANCH 22500
#define NG 20
#define PRE 2000
#define POST 300
#define TOTAL (BN * N_ANCH)      // 180000
#define HALF_RNG 90000u

// grid partition for k_front
#define NB_PROP 704   // ceil(180000/256)
#define NB_LAB  704   // 88 * 8
#define NB_GTB  160   // 8 * 20

// ---------------- device helpers ----------------

__device__ __forceinline__ void anchor_dims(int d, float& w, float& h) {
    const double scl[3] = {8.0, 16.0, 32.0};
    const double rat[3] = {0.5, 1.0, 2.0};
    double s = 16.0 * scl[d / 3];
    double r = rat[d % 3];
    w = (float)(s * sqrt(r));
    h = (float)(s * sqrt(1.0 / r));
}

__device__ __forceinline__ void anchor_corners(int n, float& x1, float& y1, float& x2, float& y2) {
    int d = n / NPOS, k = n % NPOS;
    float cx = (float)(8 + 16 * (k / FHW));
    float cy = (float)(8 + 16 * (k % FHW));
    float w, h; anchor_dims(d, w, h);
    x1 = cx - 0.5f * w; y1 = cy - 0.5f * h;
    x2 = cx + 0.5f * w; y2 = cy + 0.5f * h;
}

__device__ __forceinline__ float iou_f(float ax1, float ay1, float ax2, float ay2,
                                       float bx1, float by1, float bx2, float by2) {
    float tlx = fmaxf(ax1, bx1), tly = fmaxf(ay1, by1);
    float brx = fminf(ax2, bx2), bry = fminf(ay2, by2);
    float wx = fmaxf(brx - tlx, 0.0f);
    float wy = fmaxf(bry - tly, 0.0f);
    float inter = wx * wy;
    float a1 = (ax2 - ax1) * (ay2 - ay1);
    float a2 = (bx2 - bx1) * (by2 - by1);
    float den = fmaxf(a1 + a2 - inter, 1e-8f);
    return inter / den;
}

__device__ __forceinline__ unsigned int f32_sort_asc(float f) {
    unsigned int u = __float_as_uint(f);
    return (u & 0x80000000u) ? ~u : (u | 0x80000000u);
}

#define TF_R(r) { x0 += x1; x1 = ((x1 << r) | (x1 >> (32 - r))); x1 ^= x0; }
__device__ __forceinline__ unsigned int threefry_bits(unsigned int j) {
    unsigned int i = (j < HALF_RNG) ? j : j - HALF_RNG;
    unsigned int x0 = i, x1 = i + HALF_RNG;
    const unsigned int ks0 = 0u, ks1 = 42u, ks2 = 0x1BD11BDAu ^ 0u ^ 42u;
    x0 += ks0; x1 += ks1;
    TF_R(13) TF_R(15) TF_R(26) TF_R(6)
    x0 += ks1; x1 += ks2 + 1u;
    TF_R(17) TF_R(29) TF_R(16) TF_R(24)
    x0 += ks2; x1 += ks0 + 2u;
    TF_R(13) TF_R(15) TF_R(26) TF_R(6)
    x0 += ks0; x1 += ks1 + 3u;
    TF_R(17) TF_R(29) TF_R(16) TF_R(24)
    x0 += ks1; x1 += ks2 + 4u;
    TF_R(13) TF_R(15) TF_R(26) TF_R(6)
    x0 += ks2; x1 += ks0 + 5u;
    return (j < HALF_RNG) ? x0 : x1;
}

__device__ __forceinline__ float smooth_l1(float d) {
    float ad = fabsf(d);
    return (ad < (float)(1.0 / 9.0)) ? (4.5f * d) * d : (ad - (float)(0.5 / 9.0));
}

// block-wide u64 sum broadcast to all threads. One barrier. Caller alternates
// `buf` (0/1) between consecutive calls; sred has 32 slots. nwaves = blockDim/64.
__device__ __forceinline__ u64 block_sum_u64(u64 v, u64* sred, int buf, int nwaves) {
    for (int o = 32; o >= 1; o >>= 1) v += __shfl_down(v, o);
    int wid = threadIdx.x >> 6;
    if ((threadIdx.x & 63) == 0) sred[buf * 16 + wid] = v;
    __syncthreads();
    u64 s = 0;
    for (int i = 0; i < nwaves; ++i) s += sred[buf * 16 + i];
    return s;
}

// ---------------- fused front kernel: proposals+keys | labels+argmax | gtbest ----------------

__global__ void k_front(const float* __restrict__ pred, const float* __restrict__ cls,
                        const float* __restrict__ gt,
                        float* __restrict__ prop, u64* __restrict__ keys,
                        int* __restrict__ labels, int* __restrict__ argmax_b,
                        int* __restrict__ gt_best, double* __restrict__ acc) {
    int bid = blockIdx.x;
    if (bid == 0 && threadIdx.x < 2) acc[threadIdx.x] = 0.0;

    if (bid < NB_PROP) {
        // ---- proposals + topk keys ----
        int t = bid * 256 + threadIdx.x;
        if (t >= TOTAL) return;
        int b = t / N_ANCH, n = t % N_ANCH;
        float ax1, ay1, ax2, ay2; anchor_corners(n, ax1, ay1, ax2, ay2);
        float acx = (ax1 + ax2) * 0.5f, acy = (ay1 + ay2) * 0.5f;
        float aw = ax2 - ax1, ah = ay2 - ay1;
        int a = n % NA_T, hw = n / NA_T;
        const float* pb = pred + (size_t)b * 36 * NPOS;
        float dx = pb[(4 * a + 0) * NPOS + hw];
        float dy = pb[(4 * a + 1) * NPOS + hw];
        float dw = pb[(4 * a + 2) * NPOS + hw];
        float dh = pb[(4 * a + 3) * NPOS + hw];
        float px = acx + dx * aw, py = acy + dy * ah;
        float pw = aw * expf(dw), ph = ah * expf(dh);
        float x1 = px - 0.5f * pw, y1 = py - 0.5f * ph;
        float x2 = px + 0.5f * pw, y2 = py + 0.5f * ph;
        x1 = fminf(fmaxf(x1, 0.0f), 799.0f);
        y1 = fminf(fmaxf(y1, 0.0f), 799.0f);
        x2 = fminf(fmaxf(x2, 0.0f), 799.0f);
        y2 = fminf(fmaxf(y2, 0.0f), 799.0f);
        ((float4*)prop)[(size_t)b * N_ANCH + n] = make_float4(x1, y1, x2, y2);
        float score = cls[((size_t)b * 18 + 9 + a) * NPOS + hw];
        unsigned int kd = ~f32_sort_asc(score);   // ascending -> descending score, idx ties asc
        keys[t] = ((u64)kd << 15) | (unsigned int)n;   // 47-bit key
    } else if (bid < NB_PROP + NB_LAB) {
        // ---- per-anchor labels + argmax over GT ----
        __shared__ float4 g[NG];
        int lb = bid - NB_PROP;
        int b = lb / 88, bx = lb % 88;
        if (threadIdx.x < NG) g[threadIdx.x] = ((const float4*)gt)[b * NG + threadIdx.x];
        __syncthreads();
        int n = bx * 256 + threadIdx.x;
        if (n >= N_ANCH) return;
        float ax1, ay1, ax2, ay2; anchor_corners(n, ax1, ay1, ax2, ay2);
        float best = -1.0f; int bi = 0;
        for (int gi = 0; gi < NG; ++gi) {
            float4 G = g[gi];
            float v = iou_f(G.x, G.y, G.z, G.w, ax1, ay1, ax2, ay2);
            if (v > best) { best = v; bi = gi; }  // first-max
        }
        int lab = -1;
        if (best < 0.3f) lab = 0;
        if (best >= 0.7f) lab = 1;
        labels[b * N_ANCH + n] = lab;
        argmax_b[b * N_ANCH + n] = bi;
    } else {
        // ---- per-GT best anchor ----
        int gid = bid - NB_PROP - NB_LAB;
        int b = gid / NG, gi = gid % NG;
        float4 G = ((const float4*)gt)[b * NG + gi];
        float best = -1.0f; int bidx = N_ANCH;
        for (int n = threadIdx.x; n < N_ANCH; n += 256) {
            float ax1, ay1, ax2, ay2; anchor_corners(n, ax1, ay1, ax2, ay2);
            float v = iou_f(G.x, G.y, G.z, G.w, ax1, ay1, ax2, ay2);
            if (v > best) { best = v; bidx = n; }
        }
        __shared__ float sv[256]; __shared__ int si[256];
        sv[threadIdx.x] = best; si[threadIdx.x] = bidx;
        __syncthreads();
        for (int s = 128; s > 0; s >>= 1) {
            if (threadIdx.x < s) {
                float v2 = sv[threadIdx.x + s]; int i2 = si[threadIdx.x + s];
                if (v2 > sv[threadIdx.x] || (v2 == sv[threadIdx.x] && i2 < si[threadIdx.x])) {
                    sv[threadIdx.x] = v2; si[threadIdx.x] = i2;
                }
            }
            __syncthreads();
        }
        if (threadIdx.x == 0) gt_best[gid] = si[0];
    }
}

// ---------------- top-2000: bitwise binary-search threshold + LDS bitonic ----------------

__global__ void __launch_bounds__(1024) k_topk(const u64* __restrict__ keys,
                                               const float* __restrict__ prop,
                                               float* __restrict__ topb) {
    int b = blockIdx.x, tid = threadIdx.x;
    const u64* kb = keys + (size_t)b * N_ANCH;
    u64 mykeys[22];
    int cnt = 0;
    for (int n = tid; n < N_ANCH; n += 1024) mykeys[cnt++] = kb[n];

    __shared__ u64 sred[32];
    // T = 2000th-smallest key (keys unique): selected set = {key <= T}, |set| = 2000
    u64 T = 0;
    for (int bit = 46; bit >= 0; --bit) {
        u64 cand = T | (1ull << bit);
        unsigned int c = 0;
        for (int k = 0; k < cnt; ++k) c += (mykeys[k] < cand) ? 1u : 0u;
        u64 tot = block_sum_u64((u64)c, sred, bit & 1, 16);
        if (tot < (u64)PRE) T = cand;
    }

    __shared__ u64 sk[2048];
    __shared__ unsigned int s_cnt;
    if (tid == 0) s_cnt = 0;
    for (int i = tid; i < 2048; i += 1024) sk[i] = ~0ull;
    __syncthreads();
    for (int k = 0; k < cnt; ++k)
        if (mykeys[k] <= T) { unsigned int p = atomicAdd(&s_cnt, 1u); sk[p] = mykeys[k]; }
    __syncthreads();
    // bitonic sort 2048 in LDS (ascending; ~0ull pad sorts to end)
    for (int k = 2; k <= 2048; k <<= 1) {
        for (int j = k >> 1; j > 0; j >>= 1) {
            for (int i = tid; i < 2048; i += 1024) {
                int l = i ^ j;
                if (l > i) {
                    u64 ai = sk[i], al = sk[l];
                    bool up = ((i & k) == 0);
                    if ((ai > al) == up) { sk[i] = al; sk[l] = ai; }
                }
            }
            __syncthreads();
        }
    }
    for (int i = tid; i < PRE; i += 1024) {
        int idx = (int)(sk[i] & 0x7fffu);
        ((float4*)topb)[(size_t)b * PRE + i] = ((const float4*)prop)[(size_t)b * N_ANCH + idx];
    }
}

// ---------------- NMS mask matrix (unchanged) ----------------

__global__ void k_nmsmask(const float* __restrict__ topb, u64* __restrict__ masks) {
    __shared__ float4 boxes[PRE];
    int b = blockIdx.y;
    for (int i = threadIdx.x; i < PRE; i += blockDim.x)
        boxes[i] = ((const float4*)topb)[(size_t)b * PRE + i];
    __syncthreads();
    int i = blockIdx.x * 8 + (threadIdx.x >> 5);
    int chunk = threadIdx.x & 31;
    float4 bi = boxes[i];
    u64 m = 0;
    int j0 = chunk * 64;
    for (int jj = 0; jj < 64; ++jj) {
        int j = j0 + jj;
        if (j < PRE && j > i) {
            float4 bj = boxes[j];
            if (iou_f(bi.x, bi.y, bi.z, bi.w, bj.x, bj.y, bj.z, bj.w) > 0.7f)
                m |= 1ull << jj;
        }
    }
    masks[((size_t)b * PRE + i) * 32 + chunk] = m;
}

// ---------------- NMS serial reduce with double-buffered LDS prefetch ----------------

__global__ void __launch_bounds__(256) k_nmsreduce(const u64* __restrict__ masks,
                                                   const float* __restrict__ topb,
                                                   float* __restrict__ out) {
    int b = blockIdx.x, tid = threadIdx.x;
    __shared__ u64 buf[2][2048];     // 64 rows x 32 words, double-buffered (32 KB)
    __shared__ int s_keep[POST];
    __shared__ int s_cnt;
    const u64* mb = masks + (size_t)b * PRE * 32;
    for (int e = tid; e < 2048; e += 256) buf[0][e] = mb[e];   // chunk 0
    __syncthreads();
    u64 rm = 0;        // lanes 0..31 of wave 0 own remv words 0..31
    int count = 0;
    for (int c = 0; c < 32; ++c) {
        if (tid >= 64) {
            // waves 1-3: prefetch chunk c+1 while wave 0 scans chunk c
            if (c + 1 < 32) {
                int row0 = (c + 1) * 64;
                int nel = (min(64, PRE - row0)) * 32;
                const u64* src = mb + (size_t)row0 * 32;
                u64* dst = buf[(c + 1) & 1];
                for (int e = tid - 64; e < nel; e += 192) dst[e] = src[e];
            }
        } else if (count < POST) {
            u64 cur = __shfl(rm, c);            // remv word c (chunk c == word c)
            const u64* bb = buf[c & 1];
            int jmax = min(64, PRE - c * 64);
            for (int j = 0; j < jmax; ++j) {
                if (!((cur >> j) & 1ull)) {
                    if (tid == 0) s_keep[count] = c * 64 + j;
                    u64 m = bb[j * 32 + (tid & 31)];
                    if (tid < 32) rm |= m;
                    cur |= __shfl(m, c);        // word c of accepted row
                    count++;
                    if (count >= POST) break;
                }
            }
        }
        __syncthreads();
    }
    if (tid == 0) s_cnt = count;
    __syncthreads();
    for (int s = tid; s < POST; s += 256) {
        float4 v = make_float4(0.f, 0.f, 0.f, 0.f);
        if (s < s_cnt) {
            const float* p = topb + ((size_t)b * PRE + s_keep[s]) * 4;
            v = make_float4(floorf(p[0]), floorf(p[1]), floorf(p[2]), floorf(p[3]));
        }
        ((float4*)out)[(size_t)b * POST + s] = v;
    }
}

// ---------------- fused: gtapply + inside + count + dual binary-search sample + loss ----------------

__global__ void __launch_bounds__(1024) k_sample(const int* __restrict__ labels,
                                                 const int* __restrict__ argmax_b,
                                                 const int* __restrict__ gt_best,
                                                 const float* __restrict__ pred,
                                                 const float* __restrict__ cls,
                                                 const float* __restrict__ gt,
                                                 double* __restrict__ acc,
                                                 int* __restrict__ cnt_out) {
    int b = blockIdx.x, tid = threadIdx.x;
    __shared__ int s_gtb[NG];
    __shared__ u64 sred[32];
    if (tid < NG) s_gtb[tid] = gt_best[b * NG + tid];
    __syncthreads();
    int gtb[NG];
    #pragma unroll
    for (int g = 0; g < NG; ++g) gtb[g] = s_gtb[g];

    u64 mykeys[22];
    unsigned int pm = 0, nm = 0;
    unsigned int cp = 0, cn = 0;
    int cnt = 0;
    for (int n = tid; n < N_ANCH; n += 1024) {
        int l = labels[b * N_ANCH + n];
        #pragma unroll
        for (int g = 0; g < NG; ++g) if (n == gtb[g]) l = 1;       // gt_best -> 1
        float x1, y1, x2, y2; anchor_corners(n, x1, y1, x2, y2);
        if (x1 >= 0.0f && y1 >= 0.0f && x2 <= 800.0f && y2 <= 800.0f) l = -1;  // inside -> -1
        unsigned int mant = threefry_bits((unsigned int)(b * N_ANCH + n)) >> 9;
        mykeys[cnt] = ((u64)mant << 15) | (unsigned int)n;          // 38-bit key
        if (l == 1) { pm |= 1u << cnt; cp++; }
        else if (l == 0) { nm |= 1u << cnt; cn++; }
        cnt++;
    }

    u64 packed = block_sum_u64(((u64)cp << 32) | (u64)cn, sred, 0, 16);
    int cpt = (int)(packed >> 32), ctot = (int)(packed & 0xffffffffu);
    int np = min(cpt, 128), nn = min(ctot, 256 - np);
    bool sp = (cpt > np), sn = (ctot > nn);   // need selection only if over-subscribed

    u64 Tp = 0, Tn = 0;
    if (sp || sn) {
        for (int bit = 37; bit >= 0; --bit) {
            u64 cP = Tp | (1ull << bit), cN = Tn | (1ull << bit);
            unsigned int a = 0, d = 0;
            for (int k = 0; k < cnt; ++k) {
                u64 kk = mykeys[k];
                a += ((pm >> k) & 1u) & (kk < cP ? 1u : 0u);
                d += ((nm >> k) & 1u) & (kk < cN ? 1u : 0u);
            }
            u64 t2 = block_sum_u64(((u64)a << 32) | (u64)d, sred, bit & 1, 16);
            if ((t2 >> 32) < (u64)np) Tp = cP;
            if ((t2 & 0xffffffffu) < (u64)nn) Tn = cN;
        }
    }
    if (!sp) Tp = ~0ull;   // keep all positives
    if (!sn) Tn = ~0ull;   // keep all negatives

    // inline loss over selected samples
    double lcls = 0.0, lbox = 0.0;
    int k = 0;
    for (int n = tid; n < N_ANCH; n += 1024, ++k) {
        int lab = -1;
        if (((pm >> k) & 1u) && mykeys[k] <= Tp) lab = 1;
        else if (((nm >> k) & 1u) && mykeys[k] <= Tn) lab = 0;
        if (lab < 0) continue;
        int a = n % NA_T, hw = n / NA_T;
        float l0 = cls[((size_t)b * 18 + 2 * a + 0) * NPOS + hw];
        float l1 = cls[((size_t)b * 18 + 2 * a + 1) * NPOS + hw];
        float m = fmaxf(l0, l1);
        float s0 = l0 - m, s1 = l1 - m;
        float lse = logf(expf(s0) + expf(s1));
        lcls += (double)(-((lab ? s1 : s0) - lse));
        if (lab == 1) {
            const float* pb = pred + (size_t)b * 36 * NPOS;
            float dx = pb[(4 * a + 0) * NPOS + hw];
            float dy = pb[(4 * a + 1) * NPOS + hw];
            float dw = pb[(4 * a + 2) * NPOS + hw];
            float dh = pb[(4 * a + 3) * NPOS + hw];
            float ax1, ay1, ax2, ay2; anchor_corners(n, ax1, ay1, ax2, ay2);
            float acx = (ax1 + ax2) * 0.5f, acy = (ay1 + ay2) * 0.5f;
            float aw = ax2 - ax1, ah = ay2 - ay1;
            float4 G = ((const float4*)gt)[b * NG + argmax_b[b * N_ANCH + n]];
            float gcx = (G.x + G.z) * 0.5f, gcy = (G.y + G.w) * 0.5f;
            float gw = G.z - G.x, gh = G.w - G.y;
            float t0 = (gcx - acx) / aw, t1 = (gcy - acy) / ah;
            float t2 = logf(gw / aw), t3 = logf(gh / ah);
            lbox += (double)(smooth_l1(dx - t0) + smooth_l1(dy - t1) +
                             smooth_l1(dw - t2) + smooth_l1(dh - t3));
        }
    }
    for (int o = 32; o >= 1; o >>= 1) {
        lcls += __shfl_down(lcls, o);
        lbox += __shfl_down(lbox, o);
    }
    if ((tid & 63) == 0) {
        atomicAdd(&acc[0], lcls);
        atomicAdd(&acc[1], lbox);
    }
    if (tid == 0) cnt_out[b] = np + nn;
}

__global__ void k_final(const double* __restrict__ acc, const int* __restrict__ cnt_out,
                        float* __restrict__ out) {
    if (threadIdx.x != 0 || blockIdx.x != 0) return;
    int total = 0, count0 = 0;
    for (int b = 0; b < BN; ++b) {
        total += cnt_out[b];
        if (b == 0) count0 = cnt_out[b];
    }
    out[BN * POST * 4 + 0] = (float)(acc[1] / (double)max(count0, 1));  // bbox_loss
    out[BN * POST * 4 + 1] = (float)(acc[0] / (double)max(total, 1));   // cls_loss
}

// ---------------- launch ----------------

extern "C" void kernel_launch(void* const* d_in, const int* in_sizes, int n_in,
                              void* d_out, int out_size, void* d_ws, size_t ws_size,
                              hipStream_t stream) {
    (void)in_sizes; (void)n_in; (void)out_size; (void)ws_size;
    const float* pred = (const float*)d_in[0];   // (8,36,50,50)
    const float* cls  = (const float*)d_in[1];   // (8,18,50,50)
    const float* gt   = (const float*)d_in[2];   // (8,20,4)
    float* out = (float*)d_out;                  // 9600 boxes + 2 losses

    char* w = (char*)d_ws;
    size_t off = 0;
    auto take = [&](size_t bytes) { void* p = w + off; off += (bytes + 255) & ~(size_t)255; return p; };
    float* prop       = (float*)take((size_t)TOTAL * 4 * 4);       // 2.88 MB
    u64* keys         = (u64*)take((size_t)TOTAL * 8);             // 1.44 MB
    float* topb       = (float*)take((size_t)BN * PRE * 4 * 4);    // 256 KB
    u64* masks        = (u64*)take((size_t)BN * PRE * 32 * 8);     // 4.10 MB
    int* labels       = (int*)take((size_t)TOTAL * 4);             // 720 KB
    int* argmax_b     = (int*)take((size_t)TOTAL * 4);             // 720 KB
    int* gt_best      = (int*)take((size_t)BN * NG * 4);
    int* cnt_out      = (int*)take(BN * 4);
    double* acc       = (double*)take(2 * 8);

    k_front<<<NB_PROP + NB_LAB + NB_GTB, 256, 0, stream>>>(pred, cls, gt, prop, keys,
                                                           labels, argmax_b, gt_best, acc);
    k_topk<<<BN, 1024, 0, stream>>>(keys, prop, topb);
    k_nmsmask<<<dim3(PRE / 8, BN), 256, 0, stream>>>(topb, masks);
    k_nmsreduce<<<BN, 256, 0, stream>>>(masks, topb, out);
    k_sample<<<BN, 1024, 0, stream>>>(labels, argmax_b, gt_best, pred, cls, gt, acc, cnt_out);
    k_final<<<1, 64, 0, stream>>>(acc, cnt_out, out);
}

// Round 4
// 411.306 us; speedup vs baseline: 1.9904x; 1.9904x over previous
//
#include <hip/hip_runtime.h>
#include <math.h>

typedef unsigned long long u64;

#define BN 8
#define NA_T 9
#define NPOS 2500
#define FHW 50
#define N_ANCH 22500
#define NG 20
#define PRE 2000
#define POST 300
#define TOTAL (BN * N_ANCH)      // 180000
#define HALF_RNG 90000u

// grid partition for k_front
#define NB_PROP 704   // ceil(180000/256)
#define NB_LAB  704   // 88 * 8
#define NB_GTB  160   // 8 * 20

// ---------------- device helpers ----------------

__device__ __forceinline__ void anchor_dims(int d, float& w, float& h) {
    const double scl[3] = {8.0, 16.0, 32.0};
    const double rat[3] = {0.5, 1.0, 2.0};
    double s = 16.0 * scl[d / 3];
    double r = rat[d % 3];
    w = (float)(s * sqrt(r));
    h = (float)(s * sqrt(1.0 / r));
}

__device__ __forceinline__ void anchor_corners(int n, float& x1, float& y1, float& x2, float& y2) {
    int d = n / NPOS, k = n % NPOS;
    float cx = (float)(8 + 16 * (k / FHW));
    float cy = (float)(8 + 16 * (k % FHW));
    float w, h; anchor_dims(d, w, h);
    x1 = cx - 0.5f * w; y1 = cy - 0.5f * h;
    x2 = cx + 0.5f * w; y2 = cy + 0.5f * h;
}

__device__ __forceinline__ float iou_f(float ax1, float ay1, float ax2, float ay2,
                                       float bx1, float by1, float bx2, float by2) {
    float tlx = fmaxf(ax1, bx1), tly = fmaxf(ay1, by1);
    float brx = fminf(ax2, bx2), bry = fminf(ay2, by2);
    float wx = fmaxf(brx - tlx, 0.0f);
    float wy = fmaxf(bry - tly, 0.0f);
    float inter = wx * wy;
    float a1 = (ax2 - ax1) * (ay2 - ay1);
    float a2 = (bx2 - bx1) * (by2 - by1);
    float den = fmaxf(a1 + a2 - inter, 1e-8f);
    return inter / den;
}

__device__ __forceinline__ unsigned int f32_sort_asc(float f) {
    unsigned int u = __float_as_uint(f);
    return (u & 0x80000000u) ? ~u : (u | 0x80000000u);
}

#define TF_R(r) { x0 += x1; x1 = ((x1 << r) | (x1 >> (32 - r))); x1 ^= x0; }
__device__ __forceinline__ unsigned int threefry_bits(unsigned int j) {
    unsigned int i = (j < HALF_RNG) ? j : j - HALF_RNG;
    unsigned int x0 = i, x1 = i + HALF_RNG;
    const unsigned int ks0 = 0u, ks1 = 42u, ks2 = 0x1BD11BDAu ^ 0u ^ 42u;
    x0 += ks0; x1 += ks1;
    TF_R(13) TF_R(15) TF_R(26) TF_R(6)
    x0 += ks1; x1 += ks2 + 1u;
    TF_R(17) TF_R(29) TF_R(16) TF_R(24)
    x0 += ks2; x1 += ks0 + 2u;
    TF_R(13) TF_R(15) TF_R(26) TF_R(6)
    x0 += ks0; x1 += ks1 + 3u;
    TF_R(17) TF_R(29) TF_R(16) TF_R(24)
    x0 += ks1; x1 += ks2 + 4u;
    TF_R(13) TF_R(15) TF_R(26) TF_R(6)
    x0 += ks2; x1 += ks0 + 5u;
    return (j < HALF_RNG) ? x0 : x1;
}

__device__ __forceinline__ float smooth_l1(float d) {
    float ad = fabsf(d);
    return (ad < (float)(1.0 / 9.0)) ? (4.5f * d) * d : (ad - (float)(0.5 / 9.0));
}

// block-wide u64 sum broadcast. One barrier. sred has 16 slots (nwaves<=16).
__device__ __forceinline__ u64 block_sum_u64(u64 v, u64* sred, int nwaves) {
    for (int o = 32; o >= 1; o >>= 1) v += __shfl_down(v, o);
    int wid = threadIdx.x >> 6;
    if ((threadIdx.x & 63) == 0) sred[wid] = v;
    __syncthreads();
    u64 s = 0;
    for (int i = 0; i < nwaves; ++i) s += sred[i];
    return s;
}

// After hist[0..nb) is filled: find digit bin containing rank `remaining`
// (1-indexed) and the residual rank within it. Wave 0 computes; result in
// s_out[0]=digit, s_out[1]=new remaining. All threads call (barrier inside).
// nb must be a multiple of 64.
__device__ __forceinline__ void hist_pick(const unsigned int* hist, int nb,
                                          unsigned int remaining, unsigned int* s_out) {
    if (threadIdx.x < 64) {
        int lane = threadIdx.x;
        int bpl = nb >> 6;
        int base = lane * bpl;
        unsigned int s = 0;
        for (int i = 0; i < bpl; ++i) s += hist[base + i];
        unsigned int p = s;   // inclusive prefix across lanes
        for (int o = 1; o < 64; o <<= 1) {
            unsigned int t = __shfl_up(p, o);
            if (lane >= o) p += t;
        }
        unsigned int e = p - s;  // exclusive
        if (e < remaining && remaining <= p) {
            unsigned int cum = e;
            for (int i = 0; i < bpl; ++i) {
                unsigned int h = hist[base + i];
                if (cum + h >= remaining) {
                    s_out[0] = (unsigned int)(base + i);
                    s_out[1] = remaining - cum;
                    break;
                }
                cum += h;
            }
        }
    }
    __syncthreads();
}

// ---------------- fused front kernel: proposals+kd | labels+argmax | gtbest ----------------

__global__ void k_front(const float* __restrict__ pred, const float* __restrict__ cls,
                        const float* __restrict__ gt,
                        float* __restrict__ prop, unsigned int* __restrict__ kd_g,
                        int* __restrict__ labels, int* __restrict__ argmax_b,
                        int* __restrict__ gt_best, double* __restrict__ acc) {
    int bid = blockIdx.x;
    if (bid == 0 && threadIdx.x < 2) acc[threadIdx.x] = 0.0;

    if (bid < NB_PROP) {
        int t = bid * 256 + threadIdx.x;
        if (t >= TOTAL) return;
        int b = t / N_ANCH, n = t % N_ANCH;
        float ax1, ay1, ax2, ay2; anchor_corners(n, ax1, ay1, ax2, ay2);
        float acx = (ax1 + ax2) * 0.5f, acy = (ay1 + ay2) * 0.5f;
        float aw = ax2 - ax1, ah = ay2 - ay1;
        int a = n % NA_T, hw = n / NA_T;
        const float* pb = pred + (size_t)b * 36 * NPOS;
        float dx = pb[(4 * a + 0) * NPOS + hw];
        float dy = pb[(4 * a + 1) * NPOS + hw];
        float dw = pb[(4 * a + 2) * NPOS + hw];
        float dh = pb[(4 * a + 3) * NPOS + hw];
        float px = acx + dx * aw, py = acy + dy * ah;
        float pw = aw * expf(dw), ph = ah * expf(dh);
        float x1 = px - 0.5f * pw, y1 = py - 0.5f * ph;
        float x2 = px + 0.5f * pw, y2 = py + 0.5f * ph;
        x1 = fminf(fmaxf(x1, 0.0f), 799.0f);
        y1 = fminf(fmaxf(y1, 0.0f), 799.0f);
        x2 = fminf(fmaxf(x2, 0.0f), 799.0f);
        y2 = fminf(fmaxf(y2, 0.0f), 799.0f);
        ((float4*)prop)[(size_t)b * N_ANCH + n] = make_float4(x1, y1, x2, y2);
        float score = cls[((size_t)b * 18 + 9 + a) * NPOS + hw];
        kd_g[t] = ~f32_sort_asc(score);   // ascending (kd<<15|n) == lax.top_k order
    } else if (bid < NB_PROP + NB_LAB) {
        __shared__ float4 g[NG];
        int lb = bid - NB_PROP;
        int b = lb / 88, bx = lb % 88;
        if (threadIdx.x < NG) g[threadIdx.x] = ((const float4*)gt)[b * NG + threadIdx.x];
        __syncthreads();
        int n = bx * 256 + threadIdx.x;
        if (n >= N_ANCH) return;
        float ax1, ay1, ax2, ay2; anchor_corners(n, ax1, ay1, ax2, ay2);
        float best = -1.0f; int bi = 0;
        for (int gi = 0; gi < NG; ++gi) {
            float4 G = g[gi];
            float v = iou_f(G.x, G.y, G.z, G.w, ax1, ay1, ax2, ay2);
            if (v > best) { best = v; bi = gi; }  // first-max
        }
        int lab = -1;
        if (best < 0.3f) lab = 0;
        if (best >= 0.7f) lab = 1;
        labels[b * N_ANCH + n] = lab;
        argmax_b[b * N_ANCH + n] = bi;
    } else {
        int gid = bid - NB_PROP - NB_LAB;
        int b = gid / NG, gi = gid % NG;
        float4 G = ((const float4*)gt)[b * NG + gi];
        float best = -1.0f; int bidx = N_ANCH;
        for (int n = threadIdx.x; n < N_ANCH; n += 256) {
            float ax1, ay1, ax2, ay2; anchor_corners(n, ax1, ay1, ax2, ay2);
            float v = iou_f(G.x, G.y, G.z, G.w, ax1, ay1, ax2, ay2);
            if (v > best) { best = v; bidx = n; }
        }
        __shared__ float sv[256]; __shared__ int si[256];
        sv[threadIdx.x] = best; si[threadIdx.x] = bidx;
        __syncthreads();
        for (int s = 128; s > 0; s >>= 1) {
            if (threadIdx.x < s) {
                float v2 = sv[threadIdx.x + s]; int i2 = si[threadIdx.x + s];
                if (v2 > sv[threadIdx.x] || (v2 == sv[threadIdx.x] && i2 < si[threadIdx.x])) {
                    sv[threadIdx.x] = v2; si[threadIdx.x] = i2;
                }
            }
            __syncthreads();
        }
        if (threadIdx.x == 0) gt_best[gid] = si[0];
    }
}

// ---------------- top-2000: 4-pass wide-digit radix select + LDS bitonic ----------------

__global__ void __launch_bounds__(1024) k_topk(const unsigned int* __restrict__ kd_g,
                                               const float* __restrict__ prop,
                                               float* __restrict__ topb) {
    int b = blockIdx.x, tid = threadIdx.x;
    const unsigned int* kb = kd_g + (size_t)b * N_ANCH;

    // keys in true registers: fixed trip count, constant indices only
    u64 K[22];
    #pragma unroll
    for (int c = 0; c < 22; ++c) {
        int n = tid + c * 1024;
        K[c] = (n < N_ANCH) ? ((((u64)kb[n]) << 15) | (unsigned int)n) : ~0ull;  // 47-bit key
    }

    __shared__ unsigned int hist[4096];
    __shared__ unsigned int s_out[2];
    __shared__ unsigned int s_cnt;
    __shared__ u64 sk[2048];

    // radix select: digits of 12,12,12,11 bits
    u64 prefix = 0;
    unsigned int remaining = PRE;
    for (int p = 0; p < 4; ++p) {
        int sh = (p < 3) ? (35 - 12 * p) : 0;
        int bitsp = (p < 3) ? 12 : 11;
        int nb = 1 << bitsp;
        for (int i = tid; i < nb; i += 1024) hist[i] = 0;
        __syncthreads();
        u64 himask = ~((1ull << (sh + bitsp)) - 1);
        #pragma unroll
        for (int c = 0; c < 22; ++c) {
            u64 kk = K[c];
            if ((kk & himask) == prefix)
                atomicAdd(&hist[(unsigned int)((kk >> sh) & (u64)(nb - 1))], 1u);
        }
        __syncthreads();
        hist_pick(hist, nb, remaining, s_out);
        prefix |= ((u64)s_out[0]) << sh;
        remaining = s_out[1];
        __syncthreads();
    }
    u64 T = prefix;   // exact 2000th-smallest key; selected set {K <= T}, size 2000

    if (tid == 0) s_cnt = 0;
    for (int i = tid; i < 2048; i += 1024) sk[i] = ~0ull;
    __syncthreads();
    #pragma unroll
    for (int c = 0; c < 22; ++c)
        if (K[c] <= T) { unsigned int pp = atomicAdd(&s_cnt, 1u); sk[pp] = K[c]; }
    __syncthreads();
    // bitonic sort 2048 in LDS (ascending; ~0ull pad sorts to end)
    for (int k = 2; k <= 2048; k <<= 1) {
        for (int j = k >> 1; j > 0; j >>= 1) {
            for (int i = tid; i < 2048; i += 1024) {
                int l = i ^ j;
                if (l > i) {
                    u64 ai = sk[i], al = sk[l];
                    bool up = ((i & k) == 0);
                    if ((ai > al) == up) { sk[i] = al; sk[l] = ai; }
                }
            }
            __syncthreads();
        }
    }
    for (int i = tid; i < PRE; i += 1024) {
        int idx = (int)(sk[i] & 0x7fffu);
        ((float4*)topb)[(size_t)b * PRE + i] = ((const float4*)prop)[(size_t)b * N_ANCH + idx];
    }
}

// ---------------- NMS mask matrix ----------------

__global__ void k_nmsmask(const float* __restrict__ topb, u64* __restrict__ masks) {
    __shared__ float4 boxes[PRE];
    int b = blockIdx.y;
    for (int i = threadIdx.x; i < PRE; i += blockDim.x)
        boxes[i] = ((const float4*)topb)[(size_t)b * PRE + i];
    __syncthreads();
    int i = blockIdx.x * 8 + (threadIdx.x >> 5);
    int chunk = threadIdx.x & 31;
    float4 bi = boxes[i];
    u64 m = 0;
    int j0 = chunk * 64;
    for (int jj = 0; jj < 64; ++jj) {
        int j = j0 + jj;
        if (j < PRE && j > i) {
            float4 bj = boxes[j];
            if (iou_f(bi.x, bi.y, bi.z, bi.w, bj.x, bj.y, bj.z, bj.w) > 0.7f)
                m |= 1ull << jj;
        }
    }
    masks[((size_t)b * PRE + i) * 32 + chunk] = m;
}

// ---------------- NMS serial reduce with double-buffered LDS prefetch ----------------

__global__ void __launch_bounds__(256) k_nmsreduce(const u64* __restrict__ masks,
                                                   const float* __restrict__ topb,
                                                   float* __restrict__ out) {
    int b = blockIdx.x, tid = threadIdx.x;
    __shared__ u64 buf[2][2048];     // 64 rows x 32 words, double-buffered (32 KB)
    __shared__ int s_keep[POST];
    __shared__ int s_cnt;
    const u64* mb = masks + (size_t)b * PRE * 32;
    for (int e = tid; e < 2048; e += 256) buf[0][e] = mb[e];   // chunk 0
    __syncthreads();
    u64 rm = 0;        // lanes 0..31 of wave 0 own remv words 0..31
    int count = 0;
    for (int c = 0; c < 32; ++c) {
        if (tid >= 64) {
            if (c + 1 < 32) {
                int row0 = (c + 1) * 64;
                int nel = (min(64, PRE - row0)) * 32;
                const u64* src = mb + (size_t)row0 * 32;
                u64* dst = buf[(c + 1) & 1];
                for (int e = tid - 64; e < nel; e += 192) dst[e] = src[e];
            }
        } else if (count < POST) {
            u64 cur = __shfl(rm, c);            // remv word c
            const u64* bb = buf[c & 1];
            int jmax = min(64, PRE - c * 64);
            for (int j = 0; j < jmax; ++j) {
                if (!((cur >> j) & 1ull)) {
                    if (tid == 0) s_keep[count] = c * 64 + j;
                    u64 m = bb[j * 32 + (tid & 31)];
                    if (tid < 32) rm |= m;
                    cur |= __shfl(m, c);        // word c of accepted row
                    count++;
                    if (count >= POST) break;
                }
            }
        }
        __syncthreads();
    }
    if (tid == 0) s_cnt = count;
    __syncthreads();
    for (int s = tid; s < POST; s += 256) {
        float4 v = make_float4(0.f, 0.f, 0.f, 0.f);
        if (s < s_cnt) {
            const float* p = topb + ((size_t)b * PRE + s_keep[s]) * 4;
            v = make_float4(floorf(p[0]), floorf(p[1]), floorf(p[2]), floorf(p[3]));
        }
        ((float4*)out)[(size_t)b * POST + s] = v;
    }
}

// ---------------- fused: gtapply + inside + count + radix-select sample + loss ----------------

__global__ void __launch_bounds__(1024) k_sample(const int* __restrict__ labels,
                                                 const int* __restrict__ argmax_b,
                                                 const int* __restrict__ gt_best,
                                                 const float* __restrict__ pred,
                                                 const float* __restrict__ cls,
                                                 const float* __restrict__ gt,
                                                 double* __restrict__ acc,
                                                 int* __restrict__ cnt_out) {
    int b = blockIdx.x, tid = threadIdx.x;
    __shared__ int s_gtb[NG];
    __shared__ u64 sred[16];
    __shared__ unsigned int hist[2048];
    __shared__ unsigned int s_out[2];
    if (tid < NG) s_gtb[tid] = gt_best[b * NG + tid];
    __syncthreads();
    int gtb[NG];
    #pragma unroll
    for (int g = 0; g < NG; ++g) gtb[g] = s_gtb[g];

    unsigned int mant[22];      // threefry mantissa bits, true registers
    unsigned int pm = 0, nm = 0;
    unsigned int cp = 0, cn = 0;
    #pragma unroll
    for (int c = 0; c < 22; ++c) {
        int n = tid + c * 1024;
        unsigned int mv = 0;
        if (n < N_ANCH) {
            int l = labels[b * N_ANCH + n];
            #pragma unroll
            for (int g = 0; g < NG; ++g) if (n == gtb[g]) l = 1;       // gt_best -> 1
            float x1, y1, x2, y2; anchor_corners(n, x1, y1, x2, y2);
            if (x1 >= 0.0f && y1 >= 0.0f && x2 <= 800.0f && y2 <= 800.0f) l = -1;  // inside -> -1
            mv = threefry_bits((unsigned int)(b * N_ANCH + n)) >> 9;
            if (l == 1) { pm |= 1u << c; cp++; }
            else if (l == 0) { nm |= 1u << c; cn++; }
        }
        mant[c] = mv;
    }

    u64 packed = block_sum_u64(((u64)cp << 32) | (u64)cn, sred, 16);
    int cpt = (int)(packed >> 32), ctot = (int)(packed & 0xffffffffu);
    int np = min(cpt, 128), nn = min(ctot, 256 - np);
    bool sp = (cpt > np), sn = (ctot > nn);

    // radix select thresholds over 38-bit keys (mant<<15)|n: digits 11,9,9,9
    u64 T[2] = { ~0ull, ~0ull };   // T[0]=Tp, T[1]=Tn
    for (int which = 0; which < 2; ++which) {
        bool need = which ? sn : sp;
        if (!need) continue;
        unsigned int msk = which ? nm : pm;
        unsigned int remaining = (unsigned int)(which ? nn : np);
        u64 prefix = 0;
        for (int p = 0; p < 4; ++p) {
            int sh = (p == 0) ? 27 : (3 - p) * 9;
            int bitsp = (p == 0) ? 11 : 9;
            int nb = 1 << bitsp;
            for (int i = tid; i < nb; i += 1024) hist[i] = 0;
            __syncthreads();
            u64 himask = ~((1ull << (sh + bitsp)) - 1);
            #pragma unroll
            for (int c = 0; c < 22; ++c) {
                if ((msk >> c) & 1u) {
                    u64 kk = (((u64)mant[c]) << 15) | (unsigned int)(tid + c * 1024);
                    if ((kk & himask) == prefix)
                        atomicAdd(&hist[(unsigned int)((kk >> sh) & (u64)(nb - 1))], 1u);
                }
            }
            __syncthreads();
            hist_pick(hist, nb, remaining, s_out);
            prefix |= ((u64)s_out[0]) << sh;
            remaining = s_out[1];
            __syncthreads();
        }
        T[which] = prefix;
    }

    // inline loss over selected samples
    double lcls = 0.0, lbox = 0.0;
    #pragma unroll
    for (int c = 0; c < 22; ++c) {
        int n = tid + c * 1024;
        if (n >= N_ANCH) continue;
        u64 kk = (((u64)mant[c]) << 15) | (unsigned int)n;
        int lab = -1;
        if (((pm >> c) & 1u) && kk <= T[0]) lab = 1;
        else if (((nm >> c) & 1u) && kk <= T[1]) lab = 0;
        if (lab < 0) continue;
        int a = n % NA_T, hw = n / NA_T;
        float l0 = cls[((size_t)b * 18 + 2 * a + 0) * NPOS + hw];
        float l1 = cls[((size_t)b * 18 + 2 * a + 1) * NPOS + hw];
        float m = fmaxf(l0, l1);
        float s0 = l0 - m, s1 = l1 - m;
        float lse = logf(expf(s0) + expf(s1));
        lcls += (double)(-((lab ? s1 : s0) - lse));
        if (lab == 1) {
            const float* pb = pred + (size_t)b * 36 * NPOS;
            float dx = pb[(4 * a + 0) * NPOS + hw];
            float dy = pb[(4 * a + 1) * NPOS + hw];
            float dw = pb[(4 * a + 2) * NPOS + hw];
            float dh = pb[(4 * a + 3) * NPOS + hw];
            float ax1, ay1, ax2, ay2; anchor_corners(n, ax1, ay1, ax2, ay2);
            float acx = (ax1 + ax2) * 0.5f, acy = (ay1 + ay2) * 0.5f;
            float aw = ax2 - ax1, ah = ay2 - ay1;
            float4 G = ((const float4*)gt)[b * NG + argmax_b[b * N_ANCH + n]];
            float gcx = (G.x + G.z) * 0.5f, gcy = (G.y + G.w) * 0.5f;
            float gw = G.z - G.x, gh = G.w - G.y;
            float t0 = (gcx - acx) / aw, t1 = (gcy - acy) / ah;
            float t2 = logf(gw / aw), t3 = logf(gh / ah);
            lbox += (double)(smooth_l1(dx - t0) + smooth_l1(dy - t1) +
                             smooth_l1(dw - t2) + smooth_l1(dh - t3));
        }
    }
    for (int o = 32; o >= 1; o >>= 1) {
        lcls += __shfl_down(lcls, o);
        lbox += __shfl_down(lbox, o);
    }
    if ((tid & 63) == 0) {
        atomicAdd(&acc[0], lcls);
        atomicAdd(&acc[1], lbox);
    }
    if (tid == 0) cnt_out[b] = np + nn;
}

__global__ void k_final(const double* __restrict__ acc, const int* __restrict__ cnt_out,
                        float* __restrict__ out) {
    if (threadIdx.x != 0 || blockIdx.x != 0) return;
    int total = 0, count0 = 0;
    for (int b = 0; b < BN; ++b) {
        total += cnt_out[b];
        if (b == 0) count0 = cnt_out[b];
    }
    out[BN * POST * 4 + 0] = (float)(acc[1] / (double)max(count0, 1));  // bbox_loss
    out[BN * POST * 4 + 1] = (float)(acc[0] / (double)max(total, 1));   // cls_loss
}

// ---------------- launch ----------------

extern "C" void kernel_launch(void* const* d_in, const int* in_sizes, int n_in,
                              void* d_out, int out_size, void* d_ws, size_t ws_size,
                              hipStream_t stream) {
    (void)in_sizes; (void)n_in; (void)out_size; (void)ws_size;
    const float* pred = (const float*)d_in[0];   // (8,36,50,50)
    const float* cls  = (const float*)d_in[1];   // (8,18,50,50)
    const float* gt   = (const float*)d_in[2];   // (8,20,4)
    float* out = (float*)d_out;                  // 9600 boxes + 2 losses

    char* w = (char*)d_ws;
    size_t off = 0;
    auto take = [&](size_t bytes) { void* p = w + off; off += (bytes + 255) & ~(size_t)255; return p; };
    float* prop         = (float*)take((size_t)TOTAL * 4 * 4);       // 2.88 MB
    unsigned int* kd_g  = (unsigned int*)take((size_t)TOTAL * 4);    // 720 KB
    float* topb         = (float*)take((size_t)BN * PRE * 4 * 4);    // 256 KB
    u64* masks          = (u64*)take((size_t)BN * PRE * 32 * 8);     // 4.10 MB
    int* labels         = (int*)take((size_t)TOTAL * 4);             // 720 KB
    int* argmax_b       = (int*)take((size_t)TOTAL * 4);             // 720 KB
    int* gt_best        = (int*)take((size_t)BN * NG * 4);
    int* cnt_out        = (int*)take(BN * 4);
    double* acc         = (double*)take(2 * 8);

    k_front<<<NB_PROP + NB_LAB + NB_GTB, 256, 0, stream>>>(pred, cls, gt, prop, kd_g,
                                                           labels, argmax_b, gt_best, acc);
    k_topk<<<BN, 1024, 0, stream>>>(kd_g, prop, topb);
    k_nmsmask<<<dim3(PRE / 8, BN), 256, 0, stream>>>(topb, masks);
    k_nmsreduce<<<BN, 256, 0, stream>>>(masks, topb, out);
    k_sample<<<BN, 1024, 0, stream>>>(labels, argmax_b, gt_best, pred, cls, gt, acc, cnt_out);
    k_final<<<1, 64, 0, stream>>>(acc, cnt_out, out);
}

// Round 5
// 338.024 us; speedup vs baseline: 2.4219x; 1.2168x over previous
//
#include <hip/hip_runtime.h>
#include <math.h>

typedef unsigned long long u64;

#define BN 8
#define NA_T 9
#define NPOS 2500
#define FHW 50
#define N_ANCH 22500
#define NG 20
#define PRE 2000
#define POST 300
#define TOTAL (BN * N_ANCH)      // 180000
#define HALF_RNG 90000u

// grid partition for k_front
#define NB_PROP 704   // ceil(180000/256)
#define NB_LAB  704   // 88 * 8
#define NB_GTB  160   // 8 * 20

#define MR 33         // padded row stride (u64) for nmsreduce LDS

// ---------------- device helpers ----------------

__device__ __forceinline__ void anchor_dims(int d, float& w, float& h) {
    const double scl[3] = {8.0, 16.0, 32.0};
    const double rat[3] = {0.5, 1.0, 2.0};
    double s = 16.0 * scl[d / 3];
    double r = rat[d % 3];
    w = (float)(s * sqrt(r));
    h = (float)(s * sqrt(1.0 / r));
}

__device__ __forceinline__ void anchor_corners(int n, float& x1, float& y1, float& x2, float& y2) {
    int d = n / NPOS, k = n % NPOS;
    float cx = (float)(8 + 16 * (k / FHW));
    float cy = (float)(8 + 16 * (k % FHW));
    float w, h; anchor_dims(d, w, h);
    x1 = cx - 0.5f * w; y1 = cy - 0.5f * h;
    x2 = cx + 0.5f * w; y2 = cy + 0.5f * h;
}

__device__ __forceinline__ float iou_f(float ax1, float ay1, float ax2, float ay2,
                                       float bx1, float by1, float bx2, float by2) {
    float tlx = fmaxf(ax1, bx1), tly = fmaxf(ay1, by1);
    float brx = fminf(ax2, bx2), bry = fminf(ay2, by2);
    float wx = fmaxf(brx - tlx, 0.0f);
    float wy = fmaxf(bry - tly, 0.0f);
    float inter = wx * wy;
    float a1 = (ax2 - ax1) * (ay2 - ay1);
    float a2 = (bx2 - bx1) * (by2 - by1);
    float den = fmaxf(a1 + a2 - inter, 1e-8f);
    return inter / den;
}

__device__ __forceinline__ unsigned int f32_sort_asc(float f) {
    unsigned int u = __float_as_uint(f);
    return (u & 0x80000000u) ? ~u : (u | 0x80000000u);
}

#define TF_R(r) { x0 += x1; x1 = ((x1 << r) | (x1 >> (32 - r))); x1 ^= x0; }
__device__ __forceinline__ unsigned int threefry_bits(unsigned int j) {
    unsigned int i = (j < HALF_RNG) ? j : j - HALF_RNG;
    unsigned int x0 = i, x1 = i + HALF_RNG;
    const unsigned int ks0 = 0u, ks1 = 42u, ks2 = 0x1BD11BDAu ^ 0u ^ 42u;
    x0 += ks0; x1 += ks1;
    TF_R(13) TF_R(15) TF_R(26) TF_R(6)
    x0 += ks1; x1 += ks2 + 1u;
    TF_R(17) TF_R(29) TF_R(16) TF_R(24)
    x0 += ks2; x1 += ks0 + 2u;
    TF_R(13) TF_R(15) TF_R(26) TF_R(6)
    x0 += ks0; x1 += ks1 + 3u;
    TF_R(17) TF_R(29) TF_R(16) TF_R(24)
    x0 += ks1; x1 += ks2 + 4u;
    TF_R(13) TF_R(15) TF_R(26) TF_R(6)
    x0 += ks2; x1 += ks0 + 5u;
    return (j < HALF_RNG) ? x0 : x1;
}

__device__ __forceinline__ float smooth_l1(float d) {
    float ad = fabsf(d);
    return (ad < (float)(1.0 / 9.0)) ? (4.5f * d) * d : (ad - (float)(0.5 / 9.0));
}

// block-wide u64 sum broadcast. sred has 16 slots (nwaves<=16).
__device__ __forceinline__ u64 block_sum_u64(u64 v, u64* sred, int nwaves) {
    for (int o = 32; o >= 1; o >>= 1) v += __shfl_down(v, o);
    int wid = threadIdx.x >> 6;
    if ((threadIdx.x & 63) == 0) sred[wid] = v;
    __syncthreads();
    u64 s = 0;
    for (int i = 0; i < nwaves; ++i) s += sred[i];
    return s;
}

// After hist[0..nb) filled: find bin containing rank `remaining` (1-indexed) and
// residual rank. Wave 0 computes; result in s_out[0]=digit, s_out[1]=remaining.
// All threads call (barrier inside). nb multiple of 64.
__device__ __forceinline__ void hist_pick(const unsigned int* hist, int nb,
                                          unsigned int remaining, unsigned int* s_out) {
    if (threadIdx.x < 64) {
        int lane = threadIdx.x;
        int bpl = nb >> 6;
        int base = lane * bpl;
        unsigned int s = 0;
        for (int i = 0; i < bpl; ++i) s += hist[base + i];
        unsigned int p = s;
        for (int o = 1; o < 64; o <<= 1) {
            unsigned int t = __shfl_up(p, o);
            if (lane >= o) p += t;
        }
        unsigned int e = p - s;
        if (e < remaining && remaining <= p) {
            unsigned int cum = e;
            for (int i = 0; i < bpl; ++i) {
                unsigned int h = hist[base + i];
                if (cum + h >= remaining) {
                    s_out[0] = (unsigned int)(base + i);
                    s_out[1] = remaining - cum;
                    break;
                }
                cum += h;
            }
        }
    }
    __syncthreads();
}

// ---------------- fused front: proposals+kd+mant | labels(enc)+argmax | gtbest ----------------

__global__ void k_front(const float* __restrict__ pred, const float* __restrict__ cls,
                        const float* __restrict__ gt,
                        float* __restrict__ prop, unsigned int* __restrict__ kd_g,
                        unsigned int* __restrict__ mant_g,
                        int* __restrict__ labels, int* __restrict__ argmax_b,
                        int* __restrict__ gt_best, double* __restrict__ acc) {
    int bid = blockIdx.x;
    if (bid == 0 && threadIdx.x < 2) acc[threadIdx.x] = 0.0;

    if (bid < NB_PROP) {
        int t = bid * 256 + threadIdx.x;
        if (t >= TOTAL) return;
        int b = t / N_ANCH, n = t % N_ANCH;
        float ax1, ay1, ax2, ay2; anchor_corners(n, ax1, ay1, ax2, ay2);
        float acx = (ax1 + ax2) * 0.5f, acy = (ay1 + ay2) * 0.5f;
        float aw = ax2 - ax1, ah = ay2 - ay1;
        int a = n % NA_T, hw = n / NA_T;
        const float* pb = pred + (size_t)b * 36 * NPOS;
        float dx = pb[(4 * a + 0) * NPOS + hw];
        float dy = pb[(4 * a + 1) * NPOS + hw];
        float dw = pb[(4 * a + 2) * NPOS + hw];
        float dh = pb[(4 * a + 3) * NPOS + hw];
        float px = acx + dx * aw, py = acy + dy * ah;
        float pw = aw * expf(dw), ph = ah * expf(dh);
        float x1 = px - 0.5f * pw, y1 = py - 0.5f * ph;
        float x2 = px + 0.5f * pw, y2 = py + 0.5f * ph;
        x1 = fminf(fmaxf(x1, 0.0f), 799.0f);
        y1 = fminf(fmaxf(y1, 0.0f), 799.0f);
        x2 = fminf(fmaxf(x2, 0.0f), 799.0f);
        y2 = fminf(fmaxf(y2, 0.0f), 799.0f);
        ((float4*)prop)[(size_t)b * N_ANCH + n] = make_float4(x1, y1, x2, y2);
        float score = cls[((size_t)b * 18 + 9 + a) * NPOS + hw];
        kd_g[t] = ~f32_sort_asc(score);                    // asc (kd<<15|n) == lax.top_k order
        mant_g[t] = threefry_bits((unsigned int)t) >> 9;   // jax uniform mantissa bits
    } else if (bid < NB_PROP + NB_LAB) {
        __shared__ float4 g[NG];
        int lb = bid - NB_PROP;
        int b = lb / 88, bx = lb % 88;
        if (threadIdx.x < NG) g[threadIdx.x] = ((const float4*)gt)[b * NG + threadIdx.x];
        __syncthreads();
        int n = bx * 256 + threadIdx.x;
        if (n >= N_ANCH) return;
        float ax1, ay1, ax2, ay2; anchor_corners(n, ax1, ay1, ax2, ay2);
        float best = -1.0f; int bi = 0;
        for (int gi = 0; gi < NG; ++gi) {
            float4 G = g[gi];
            float v = iou_f(G.x, G.y, G.z, G.w, ax1, ay1, ax2, ay2);
            if (v > best) { best = v; bi = gi; }  // first-max
        }
        int lab = -1;
        if (best < 0.3f) lab = 0;
        if (best >= 0.7f) lab = 1;
        // inside anchors are forced to -1 LAST in reference; encode as -2 so
        // k_sample knows the gt_best->1 override must NOT apply there.
        bool inside = (ax1 >= 0.0f && ay1 >= 0.0f && ax2 <= 800.0f && ay2 <= 800.0f);
        labels[b * N_ANCH + n] = inside ? -2 : lab;
        argmax_b[b * N_ANCH + n] = bi;
    } else {
        int gid = bid - NB_PROP - NB_LAB;
        int b = gid / NG, gi = gid % NG;
        float4 G = ((const float4*)gt)[b * NG + gi];
        float best = -1.0f; int bidx = N_ANCH;
        for (int n = threadIdx.x; n < N_ANCH; n += 256) {
            float ax1, ay1, ax2, ay2; anchor_corners(n, ax1, ay1, ax2, ay2);
            float v = iou_f(G.x, G.y, G.z, G.w, ax1, ay1, ax2, ay2);
            if (v > best) { best = v; bidx = n; }
        }
        __shared__ float sv[256]; __shared__ int si[256];
        sv[threadIdx.x] = best; si[threadIdx.x] = bidx;
        __syncthreads();
        for (int s = 128; s > 0; s >>= 1) {
            if (threadIdx.x < s) {
                float v2 = sv[threadIdx.x + s]; int i2 = si[threadIdx.x + s];
                if (v2 > sv[threadIdx.x] || (v2 == sv[threadIdx.x] && i2 < si[threadIdx.x])) {
                    sv[threadIdx.x] = v2; si[threadIdx.x] = i2;
                }
            }
            __syncthreads();
        }
        if (threadIdx.x == 0) gt_best[gid] = si[0];
    }
}

// ---------------- top-2000: radix select (keys re-read from L2) + LDS bitonic ----------------

__global__ void __launch_bounds__(1024) k_topk(const unsigned int* __restrict__ kd_g,
                                               const float* __restrict__ prop,
                                               float* __restrict__ topb) {
    int b = blockIdx.x, tid = threadIdx.x;
    const unsigned int* kb = kd_g + (size_t)b * N_ANCH;

    __shared__ unsigned int hist[4096];
    __shared__ unsigned int s_out[2];
    __shared__ unsigned int s_cnt;
    __shared__ u64 sk[2048];

    // 47-bit key (kd<<15)|n ; digits 12,12,12,11
    u64 prefix = 0;
    unsigned int remaining = PRE;
    for (int p = 0; p < 4; ++p) {
        int sh = (p < 3) ? (35 - 12 * p) : 0;
        int bitsp = (p < 3) ? 12 : 11;
        int nb = 1 << bitsp;
        for (int i = tid; i < nb; i += 1024) hist[i] = 0;
        __syncthreads();
        u64 himask = ~((1ull << (sh + bitsp)) - 1);
        #pragma unroll
        for (int c = 0; c < 22; ++c) {
            int n = tid + c * 1024;
            if (n < N_ANCH) {
                u64 kk = (((u64)kb[n]) << 15) | (unsigned int)n;
                if ((kk & himask) == prefix)
                    atomicAdd(&hist[(unsigned int)((kk >> sh) & (u64)(nb - 1))], 1u);
            }
        }
        __syncthreads();
        hist_pick(hist, nb, remaining, s_out);
        prefix |= ((u64)s_out[0]) << sh;
        remaining = s_out[1];
        __syncthreads();
    }
    u64 T = prefix;   // exact 2000th-smallest; {key <= T} has size 2000

    if (tid == 0) s_cnt = 0;
    for (int i = tid; i < 2048; i += 1024) sk[i] = ~0ull;
    __syncthreads();
    #pragma unroll
    for (int c = 0; c < 22; ++c) {
        int n = tid + c * 1024;
        if (n < N_ANCH) {
            u64 kk = (((u64)kb[n]) << 15) | (unsigned int)n;
            if (kk <= T) { unsigned int pp = atomicAdd(&s_cnt, 1u); sk[pp] = kk; }
        }
    }
    __syncthreads();
    for (int k = 2; k <= 2048; k <<= 1) {
        for (int j = k >> 1; j > 0; j >>= 1) {
            for (int i = tid; i < 2048; i += 1024) {
                int l = i ^ j;
                if (l > i) {
                    u64 ai = sk[i], al = sk[l];
                    bool up = ((i & k) == 0);
                    if ((ai > al) == up) { sk[i] = al; sk[l] = ai; }
                }
            }
            __syncthreads();
        }
    }
    for (int i = tid; i < PRE; i += 1024) {
        int idx = (int)(sk[i] & 0x7fffu);
        ((float4*)topb)[(size_t)b * PRE + i] = ((const float4*)prop)[(size_t)b * N_ANCH + idx];
    }
}

// ---------------- NMS mask matrix: 16 rows/block ----------------

__global__ void __launch_bounds__(512) k_nmsmask(const float* __restrict__ topb,
                                                 u64* __restrict__ masks) {
    __shared__ float4 boxes[PRE];
    int b = blockIdx.y;
    for (int i = threadIdx.x; i < PRE; i += 512)
        boxes[i] = ((const float4*)topb)[(size_t)b * PRE + i];
    __syncthreads();
    int i = blockIdx.x * 16 + (threadIdx.x >> 5);
    int chunk = threadIdx.x & 31;
    float4 bi = boxes[i];
    u64 m = 0;
    int j0 = chunk * 64;
    for (int jj = 0; jj < 64; ++jj) {
        int j = j0 + jj;
        if (j < PRE && j > i) {
            float4 bj = boxes[j];
            if (iou_f(bi.x, bi.y, bi.z, bi.w, bj.x, bj.y, bj.z, bj.w) > 0.7f)
                m |= 1ull << jj;
        }
    }
    masks[((size_t)b * PRE + i) * 32 + chunk] = m;
}

// ---------------- NMS reduce: ffs skip-scan, deferred remv OR, early exit ----------------

__global__ void __launch_bounds__(256) k_nmsreduce(const u64* __restrict__ masks,
                                                   const float* __restrict__ topb,
                                                   float* __restrict__ out) {
    int b = blockIdx.x, tid = threadIdx.x;
    int lane = tid & 63, wid = tid >> 6;
    __shared__ u64 buf[2][64 * MR];   // stride-33 padded rows, double-buffered (~33.8 KB)
    __shared__ int s_keep[POST];
    __shared__ int s_count;
    const u64* mb = masks + (size_t)b * PRE * 32;
    for (int e = tid; e < 64 * 32; e += 256) {
        int r = e >> 5, w0 = e & 31;
        buf[0][r * MR + w0] = mb[e];
    }
    if (tid == 0) s_count = 0;
    __syncthreads();
    u64 rm = 0;            // wave 0, lanes 0..31 hold remv words 0..31
    int count = 0;
    for (int c = 0; c < 32; ++c) {
        if (wid > 0) {
            if (c + 1 < 32) {
                int row0 = (c + 1) * 64;
                int nrows = min(64, PRE - row0);
                int nel = nrows * 32;
                const u64* src = mb + (size_t)row0 * 32;
                u64* dst = buf[(c + 1) & 1];
                for (int e = tid - 64; e < nel; e += 192) {
                    int r = e >> 5, w0 = e & 31;
                    dst[r * MR + w0] = src[e];
                }
            }
        } else {
            u64* bb = buf[c & 1];
            u64 colc = bb[lane * MR + c];     // row `lane`'s word c (intra-chunk columns)
            int jmax = min(64, PRE - c * 64);
            u64 valid = (jmax >= 64) ? ~0ull : ((1ull << jmax) - 1ull);
            u64 rmc = __shfl(rm, c);
            u64 live = (~rmc) & valid;        // wave-uniform
            u64 accm = 0;
            while (live && count < POST) {
                int j = __ffsll((long long)live) - 1;
                if (lane == 0) s_keep[count] = c * 64 + j;
                count++;
                accm |= (1ull << j);
                u64 mj = __shfl(colc, j);     // row j's intra-chunk suppression word
                live &= ~mj;
                live &= ~(1ull << j);
            }
            // deferred OR of accepted rows' full masks into rm (independent reads)
            while (accm) {
                int j = __ffsll((long long)accm) - 1;
                accm &= accm - 1;
                if (lane < 32) rm |= bb[j * MR + lane];
            }
            if (lane == 0) s_count = count;
        }
        __syncthreads();
        if (s_count >= POST) break;
    }
    int cnt = s_count;
    for (int s = tid; s < POST; s += 256) {
        float4 v = make_float4(0.f, 0.f, 0.f, 0.f);
        if (s < cnt) {
            const float* p = topb + ((size_t)b * PRE + s_keep[s]) * 4;
            v = make_float4(floorf(p[0]), floorf(p[1]), floorf(p[2]), floorf(p[3]));
        }
        ((float4*)out)[(size_t)b * POST + s] = v;
    }
}

// ---------------- fused sample+loss: no private arrays, LDS tags ----------------

__global__ void __launch_bounds__(1024) k_sample(const int* __restrict__ labels,
                                                 const int* __restrict__ argmax_b,
                                                 const int* __restrict__ gt_best,
                                                 const unsigned int* __restrict__ mant_g,
                                                 const float* __restrict__ pred,
                                                 const float* __restrict__ cls,
                                                 const float* __restrict__ gt,
                                                 double* __restrict__ acc,
                                                 int* __restrict__ cnt_out) {
    int b = blockIdx.x, tid = threadIdx.x;
    __shared__ unsigned char tag_lds[22528];   // 0 neg, 1 pos, 2 ignore
    __shared__ unsigned int bitmap[704];       // gt_best membership
    __shared__ u64 sred[16];
    __shared__ unsigned int hist[2048];
    __shared__ unsigned int s_out[2];

    for (int i = tid; i < 704; i += 1024) bitmap[i] = 0;
    __syncthreads();
    if (tid < NG) {
        int gn = gt_best[b * NG + tid];
        atomicOr(&bitmap[gn >> 5], 1u << (gn & 31));
    }
    __syncthreads();

    unsigned int cp = 0, cn = 0;
    #pragma unroll
    for (int c = 0; c < 22; ++c) {
        int n = tid + c * 1024;
        if (n < N_ANCH) {
            int enc = labels[b * N_ANCH + n];
            int l = (enc == -2) ? -1 : (((bitmap[n >> 5] >> (n & 31)) & 1u) ? 1 : enc);
            tag_lds[n] = (unsigned char)((l == 1) ? 1 : ((l == 0) ? 0 : 2));
            cp += (l == 1); cn += (l == 0);
        }
    }
    __syncthreads();
    u64 packed = block_sum_u64(((u64)cp << 32) | (u64)cn, sred, 16);
    int cpt = (int)(packed >> 32), ctot = (int)(packed & 0xffffffffu);
    int np = min(cpt, 128), nn = min(ctot, 256 - np);

    const unsigned int* mg = mant_g + (size_t)b * N_ANCH;

    // radix select thresholds over 38-bit keys (mant<<15)|n: digits 11,9,9,9
    u64 T[2] = { ~0ull, ~0ull };   // T[0]=pos, T[1]=neg
    for (int which = 0; which < 2; ++which) {
        bool need = which ? (ctot > nn) : (cpt > np);
        if (!need) continue;
        unsigned int wtag = which ? 0u : 1u;
        unsigned int remaining = (unsigned int)(which ? nn : np);
        u64 prefix = 0;
        for (int p = 0; p < 4; ++p) {
            int sh = (p == 0) ? 27 : (3 - p) * 9;
            int bitsp = (p == 0) ? 11 : 9;
            int nb = 1 << bitsp;
            for (int i = tid; i < nb; i += 1024) hist[i] = 0;
            __syncthreads();
            u64 himask = ~((1ull << (sh + bitsp)) - 1);
            #pragma unroll
            for (int c = 0; c < 22; ++c) {
                int n = tid + c * 1024;
                if (n < N_ANCH && tag_lds[n] == wtag) {
                    u64 kk = (((u64)mg[n]) << 15) | (unsigned int)n;
                    if ((kk & himask) == prefix)
                        atomicAdd(&hist[(unsigned int)((kk >> sh) & (u64)(nb - 1))], 1u);
                }
            }
            __syncthreads();
            hist_pick(hist, nb, remaining, s_out);
            prefix |= ((u64)s_out[0]) << sh;
            remaining = s_out[1];
            __syncthreads();
        }
        T[which] = prefix;
    }

    // inline loss over selected samples
    double lcls = 0.0, lbox = 0.0;
    #pragma unroll
    for (int c = 0; c < 22; ++c) {
        int n = tid + c * 1024;
        if (n >= N_ANCH) continue;
        unsigned int tg = tag_lds[n];
        if (tg > 1) continue;
        u64 kk = (((u64)mg[n]) << 15) | (unsigned int)n;
        int lab = -1;
        if (tg == 1 && kk <= T[0]) lab = 1;
        else if (tg == 0 && kk <= T[1]) lab = 0;
        if (lab < 0) continue;
        int a = n % NA_T, hw = n / NA_T;
        float l0 = cls[((size_t)b * 18 + 2 * a + 0) * NPOS + hw];
        float l1 = cls[((size_t)b * 18 + 2 * a + 1) * NPOS + hw];
        float m = fmaxf(l0, l1);
        float s0 = l0 - m, s1 = l1 - m;
        float lse = logf(expf(s0) + expf(s1));
        lcls += (double)(-((lab ? s1 : s0) - lse));
        if (lab == 1) {
            const float* pb = pred + (size_t)b * 36 * NPOS;
            float dx = pb[(4 * a + 0) * NPOS + hw];
            float dy = pb[(4 * a + 1) * NPOS + hw];
            float dw = pb[(4 * a + 2) * NPOS + hw];
            float dh = pb[(4 * a + 3) * NPOS + hw];
            float ax1, ay1, ax2, ay2; anchor_corners(n, ax1, ay1, ax2, ay2);
            float acx = (ax1 + ax2) * 0.5f, acy = (ay1 + ay2) * 0.5f;
            float aw = ax2 - ax1, ah = ay2 - ay1;
            float4 G = ((const float4*)gt)[b * NG + argmax_b[b * N_ANCH + n]];
            float gcx = (G.x + G.z) * 0.5f, gcy = (G.y + G.w) * 0.5f;
            float gw = G.z - G.x, gh = G.w - G.y;
            float t0 = (gcx - acx) / aw, t1 = (gcy - acy) / ah;
            float t2 = logf(gw / aw), t3 = logf(gh / ah);
            lbox += (double)(smooth_l1(dx - t0) + smooth_l1(dy - t1) +
                             smooth_l1(dw - t2) + smooth_l1(dh - t3));
        }
    }
    for (int o = 32; o >= 1; o >>= 1) {
        lcls += __shfl_down(lcls, o);
        lbox += __shfl_down(lbox, o);
    }
    if ((tid & 63) == 0) {
        atomicAdd(&acc[0], lcls);
        atomicAdd(&acc[1], lbox);
    }
    if (tid == 0) cnt_out[b] = np + nn;
}

__global__ void k_final(const double* __restrict__ acc, const int* __restrict__ cnt_out,
                        float* __restrict__ out) {
    if (threadIdx.x != 0 || blockIdx.x != 0) return;
    int total = 0, count0 = 0;
    for (int b = 0; b < BN; ++b) {
        total += cnt_out[b];
        if (b == 0) count0 = cnt_out[b];
    }
    out[BN * POST * 4 + 0] = (float)(acc[1] / (double)max(count0, 1));  // bbox_loss
    out[BN * POST * 4 + 1] = (float)(acc[0] / (double)max(total, 1));   // cls_loss
}

// ---------------- launch ----------------

extern "C" void kernel_launch(void* const* d_in, const int* in_sizes, int n_in,
                              void* d_out, int out_size, void* d_ws, size_t ws_size,
                              hipStream_t stream) {
    (void)in_sizes; (void)n_in; (void)out_size; (void)ws_size;
    const float* pred = (const float*)d_in[0];   // (8,36,50,50)
    const float* cls  = (const float*)d_in[1];   // (8,18,50,50)
    const float* gt   = (const float*)d_in[2];   // (8,20,4)
    float* out = (float*)d_out;                  // 9600 boxes + 2 losses

    char* w = (char*)d_ws;
    size_t off = 0;
    auto take = [&](size_t bytes) { void* p = w + off; off += (bytes + 255) & ~(size_t)255; return p; };
    float* prop         = (float*)take((size_t)TOTAL * 4 * 4);       // 2.88 MB
    unsigned int* kd_g  = (unsigned int*)take((size_t)TOTAL * 4);    // 720 KB
    unsigned int* mant_g= (unsigned int*)take((size_t)TOTAL * 4);    // 720 KB
    float* topb         = (float*)take((size_t)BN * PRE * 4 * 4);    // 256 KB
    u64* masks          = (u64*)take((size_t)BN * PRE * 32 * 8);     // 4.10 MB
    int* labels         = (int*)take((size_t)TOTAL * 4);             // 720 KB
    int* argmax_b       = (int*)take((size_t)TOTAL * 4);             // 720 KB
    int* gt_best        = (int*)take((size_t)BN * NG * 4);
    int* cnt_out        = (int*)take(BN * 4);
    double* acc         = (double*)take(2 * 8);

    k_front<<<NB_PROP + NB_LAB + NB_GTB, 256, 0, stream>>>(pred, cls, gt, prop, kd_g, mant_g,
                                                           labels, argmax_b, gt_best, acc);
    k_topk<<<BN, 1024, 0, stream>>>(kd_g, prop, topb);
    k_nmsmask<<<dim3(PRE / 16, BN), 512, 0, stream>>>(topb, masks);
    k_nmsreduce<<<BN, 256, 0, stream>>>(masks, topb, out);
    k_sample<<<BN, 1024, 0, stream>>>(labels, argmax_b, gt_best, mant_g, pred, cls, gt,
                                      acc, cnt_out);
    k_final<<<1, 64, 0, stream>>>(acc, cnt_out, out);
}

// Round 8
// 272.019 us; speedup vs baseline: 3.0096x; 1.2426x over previous
//
#include <hip/hip_runtime.h>
#include <math.h>

typedef unsigned long long u64;
typedef unsigned int u32;

#define BN 8
#define NA_T 9
#define NPOS 2500
#define FHW 50
#define N_ANCH 22500
#define NG 20
#define PRE 2000
#define POST 300
#define TOTAL (BN * N_ANCH)      // 180000
#define HALF_RNG 90000u
#define SELCAP 2048

// grid partition for k_front
#define NB_PROP 704   // ceil(180000/256)
#define NB_LAB  704   // 88 * 8
#define NB_GTB  160   // 8 * 20

// ---------------- device helpers ----------------

__device__ __forceinline__ void anchor_dims(int d, float& w, float& h) {
    const double scl[3] = {8.0, 16.0, 32.0};
    const double rat[3] = {0.5, 1.0, 2.0};
    double s = 16.0 * scl[d / 3];
    double r = rat[d % 3];
    w = (float)(s * sqrt(r));
    h = (float)(s * sqrt(1.0 / r));
}

__device__ __forceinline__ void anchor_corners(int n, float& x1, float& y1, float& x2, float& y2) {
    int d = n / NPOS, k = n % NPOS;
    float cx = (float)(8 + 16 * (k / FHW));
    float cy = (float)(8 + 16 * (k % FHW));
    float w, h; anchor_dims(d, w, h);
    x1 = cx - 0.5f * w; y1 = cy - 0.5f * h;
    x2 = cx + 0.5f * w; y2 = cy + 0.5f * h;
}

__device__ __forceinline__ float iou_f(float ax1, float ay1, float ax2, float ay2,
                                       float bx1, float by1, float bx2, float by2) {
    float tlx = fmaxf(ax1, bx1), tly = fmaxf(ay1, by1);
    float brx = fminf(ax2, bx2), bry = fminf(ay2, by2);
    float wx = fmaxf(brx - tlx, 0.0f);
    float wy = fmaxf(bry - tly, 0.0f);
    float inter = wx * wy;
    float a1 = (ax2 - ax1) * (ay2 - ay1);
    float a2 = (bx2 - bx1) * (by2 - by1);
    float den = fmaxf(a1 + a2 - inter, 1e-8f);
    return inter / den;
}

__device__ __forceinline__ unsigned int f32_sort_asc(float f) {
    unsigned int u = __float_as_uint(f);
    return (u & 0x80000000u) ? ~u : (u | 0x80000000u);
}

#define TF_R(r) { x0 += x1; x1 = ((x1 << r) | (x1 >> (32 - r))); x1 ^= x0; }
__device__ __forceinline__ unsigned int threefry_bits(unsigned int j) {
    unsigned int i = (j < HALF_RNG) ? j : j - HALF_RNG;
    unsigned int x0 = i, x1 = i + HALF_RNG;
    const unsigned int ks0 = 0u, ks1 = 42u, ks2 = 0x1BD11BDAu ^ 0u ^ 42u;
    x0 += ks0; x1 += ks1;
    TF_R(13) TF_R(15) TF_R(26) TF_R(6)
    x0 += ks1; x1 += ks2 + 1u;
    TF_R(17) TF_R(29) TF_R(16) TF_R(24)
    x0 += ks2; x1 += ks0 + 2u;
    TF_R(13) TF_R(15) TF_R(26) TF_R(6)
    x0 += ks0; x1 += ks1 + 3u;
    TF_R(17) TF_R(29) TF_R(16) TF_R(24)
    x0 += ks1; x1 += ks2 + 4u;
    TF_R(13) TF_R(15) TF_R(26) TF_R(6)
    x0 += ks2; x1 += ks0 + 5u;
    return (j < HALF_RNG) ? x0 : x1;
}

__device__ __forceinline__ float smooth_l1(float d) {
    float ad = fabsf(d);
    return (ad < (float)(1.0 / 9.0)) ? (4.5f * d) * d : (ad - (float)(0.5 / 9.0));
}

// block-wide u64 sum broadcast. sred has 16 slots (nwaves<=16).
__device__ __forceinline__ u64 block_sum_u64(u64 v, u64* sred, int nwaves) {
    for (int o = 32; o >= 1; o >>= 1) v += __shfl_down(v, o);
    int wid = threadIdx.x >> 6;
    if ((threadIdx.x & 63) == 0) sred[wid] = v;
    __syncthreads();
    u64 s = 0;
    for (int i = 0; i < nwaves; ++i) s += sred[i];
    return s;
}

// After hist[0..nb) filled: find bin containing rank `remaining` (1-indexed) and
// residual rank. Wave 0 computes; result in s_out[0]=digit, s_out[1]=remaining.
// All threads call (barrier inside). nb multiple of 64.
__device__ __forceinline__ void hist_pick(const u32* hist, int nb,
                                          u32 remaining, u32* s_out) {
    if (threadIdx.x < 64) {
        int lane = threadIdx.x;
        int bpl = nb >> 6;
        int base = lane * bpl;
        u32 s = 0;
        for (int i = 0; i < bpl; ++i) s += hist[base + i];
        u32 p = s;
        for (int o = 1; o < 64; o <<= 1) {
            u32 t = __shfl_up(p, o);
            if (lane >= o) p += t;
        }
        u32 e = p - s;
        if (e < remaining && remaining <= p) {
            u32 cum = e;
            for (int i = 0; i < bpl; ++i) {
                u32 h = hist[base + i];
                if (cum + h >= remaining) {
                    s_out[0] = (u32)(base + i);
                    s_out[1] = remaining - cum;
                    break;
                }
                cum += h;
            }
        }
    }
    __syncthreads();
}

// ---------------- k_front: keys+mant | labels(enc)+argmax | gtbest ----------------

__global__ void k_front(const float* __restrict__ cls, const float* __restrict__ gt,
                        u32* __restrict__ kd_g, u32* __restrict__ mant_g,
                        int* __restrict__ labels, int* __restrict__ argmax_b,
                        int* __restrict__ gt_best, double* __restrict__ acc) {
    int bid = blockIdx.x;
    if (bid == 0 && threadIdx.x < 2) acc[threadIdx.x] = 0.0;

    if (bid < NB_PROP) {
        int t = bid * 256 + threadIdx.x;
        if (t >= TOTAL) return;
        int b = t / N_ANCH, n = t % N_ANCH;
        int a = n % NA_T, hw = n / NA_T;
        float score = cls[((size_t)b * 18 + 9 + a) * NPOS + hw];
        kd_g[t] = ~f32_sort_asc(score);                    // asc (kd<<15|n) == lax.top_k order
        mant_g[t] = threefry_bits((unsigned int)t) >> 9;   // jax uniform mantissa bits
    } else if (bid < NB_PROP + NB_LAB) {
        __shared__ float4 g[NG];
        int lb = bid - NB_PROP;
        int b = lb / 88, bx = lb % 88;
        if (threadIdx.x < NG) g[threadIdx.x] = ((const float4*)gt)[b * NG + threadIdx.x];
        __syncthreads();
        int n = bx * 256 + threadIdx.x;
        if (n >= N_ANCH) return;
        float ax1, ay1, ax2, ay2; anchor_corners(n, ax1, ay1, ax2, ay2);
        float best = -1.0f; int bi = 0;
        for (int gi = 0; gi < NG; ++gi) {
            float4 G = g[gi];
            float v = iou_f(G.x, G.y, G.z, G.w, ax1, ay1, ax2, ay2);
            if (v > best) { best = v; bi = gi; }  // first-max
        }
        int lab = -1;
        if (best < 0.3f) lab = 0;
        if (best >= 0.7f) lab = 1;
        // inside anchors forced to -1 LAST in reference; encode -2 so the
        // gt_best->1 override is known not to apply there.
        bool inside = (ax1 >= 0.0f && ay1 >= 0.0f && ax2 <= 800.0f && ay2 <= 800.0f);
        labels[b * N_ANCH + n] = inside ? -2 : lab;
        argmax_b[b * N_ANCH + n] = bi;
    } else {
        int gid = bid - NB_PROP - NB_LAB;
        int b = gid / NG, gi = gid % NG;
        float4 G = ((const float4*)gt)[b * NG + gi];
        float best = -1.0f; int bidx = N_ANCH;
        for (int d = 0; d < 9; ++d) {
            float w, h; anchor_dims(d, w, h);   // hoisted double-sqrt per d
            for (int k = threadIdx.x; k < NPOS; k += 256) {
                float cx = (float)(8 + 16 * (k / FHW));
                float cy = (float)(8 + 16 * (k % FHW));
                float x1 = cx - 0.5f * w, y1 = cy - 0.5f * h;
                float x2 = cx + 0.5f * w, y2 = cy + 0.5f * h;
                float v = iou_f(G.x, G.y, G.z, G.w, x1, y1, x2, y2);
                if (v > best) { best = v; bidx = d * NPOS + k; }  // ascending n per thread
            }
        }
        __shared__ float sv[256]; __shared__ int si[256];
        sv[threadIdx.x] = best; si[threadIdx.x] = bidx;
        __syncthreads();
        for (int s = 128; s > 0; s >>= 1) {
            if (threadIdx.x < s) {
                float v2 = sv[threadIdx.x + s]; int i2 = si[threadIdx.x + s];
                if (v2 > sv[threadIdx.x] || (v2 == sv[threadIdx.x] && i2 < si[threadIdx.x])) {
                    sv[threadIdx.x] = v2; si[threadIdx.x] = i2;
                }
            }
            __syncthreads();
        }
        if (threadIdx.x == 0) gt_best[gid] = si[0];
    }
}

// ---- k_topk: 2-level radix select + LDS bitonic + box recompute -> topb ----

__global__ void __launch_bounds__(1024) k_topk(const u32* __restrict__ kd_g,
                                               const float* __restrict__ pred,
                                               float* __restrict__ topb) {
    int b = blockIdx.x, tid = threadIdx.x;
    const u32* kb = kd_g + (size_t)b * N_ANCH;

    __shared__ u32 hist[4096];
    __shared__ u64 buf[SELCAP];
    __shared__ u64 sk[2048];
    __shared__ u32 s_out[2];
    __shared__ u32 s_cnt;
    if (tid < 2) s_out[tid] = 0;

    // 47-bit key (kd<<15)|n ; digits 12,12,12,11 ; 2-level: compact boundary bin
    u64 prefix = 0; u32 remaining = PRE; int bufcnt = -1;
    for (int p = 0; p < 4; ++p) {
        int sh = (p < 3) ? (35 - 12 * p) : 0;
        int bitsp = (p < 3) ? 12 : 11;
        int nb = 1 << bitsp;
        for (int i = tid; i < nb; i += 1024) hist[i] = 0;
        __syncthreads();
        u64 himask = ~((1ull << (sh + bitsp)) - 1);
        if (bufcnt < 0) {
            #pragma unroll
            for (int c = 0; c < 22; ++c) {
                int n = tid + c * 1024;
                if (n < N_ANCH) {
                    u64 kk = (((u64)kb[n]) << 15) | (u32)n;
                    if ((kk & himask) == prefix)
                        atomicAdd(&hist[(u32)((kk >> sh) & (u64)(nb - 1))], 1u);
                }
            }
        } else {
            for (int i = tid; i < bufcnt; i += 1024) {
                u64 kk = buf[i];
                if ((kk & himask) == prefix)
                    atomicAdd(&hist[(u32)((kk >> sh) & (u64)(nb - 1))], 1u);
            }
        }
        __syncthreads();
        hist_pick(hist, nb, remaining, s_out);
        u32 dig = s_out[0]; remaining = s_out[1];
        u32 bincnt = hist[dig];
        prefix |= ((u64)dig) << sh;
        __syncthreads();
        if (bufcnt < 0 && p < 3 && bincnt <= SELCAP) {
            if (tid == 0) s_cnt = 0;
            __syncthreads();
            u64 pmask = ~((1ull << sh) - 1);
            #pragma unroll
            for (int c = 0; c < 22; ++c) {
                int n = tid + c * 1024;
                if (n < N_ANCH) {
                    u64 kk = (((u64)kb[n]) << 15) | (u32)n;
                    if ((kk & pmask) == prefix) { u32 pos = atomicAdd(&s_cnt, 1u); buf[pos] = kk; }
                }
            }
            __syncthreads();
            bufcnt = (int)s_cnt;
        }
    }
    u64 T = prefix;   // exact: {key <= T} has size 2000

    // compact selected keys, bitonic sort 2048 in LDS
    if (tid == 0) s_cnt = 0;
    for (int i = tid; i < 2048; i += 1024) sk[i] = ~0ull;
    __syncthreads();
    #pragma unroll
    for (int c = 0; c < 22; ++c) {
        int n = tid + c * 1024;
        if (n < N_ANCH) {
            u64 kk = (((u64)kb[n]) << 15) | (u32)n;
            if (kk <= T) { u32 pp = atomicAdd(&s_cnt, 1u); sk[pp] = kk; }
        }
    }
    __syncthreads();
    for (int k = 2; k <= 2048; k <<= 1) {
        for (int j = k >> 1; j > 0; j >>= 1) {
            for (int i = tid; i < 2048; i += 1024) {
                int l = i ^ j;
                if (l > i) {
                    u64 ai = sk[i], al = sk[l];
                    bool up = ((i & k) == 0);
                    if ((ai > al) == up) { sk[i] = al; sk[l] = ai; }
                }
            }
            __syncthreads();
        }
    }

    // recompute proposal boxes for the sorted 2000 (bit-identical math), write topb
    for (int i = tid; i < PRE; i += 1024) {
        int n = (int)(sk[i] & 0x7fffu);
        float ax1, ay1, ax2, ay2; anchor_corners(n, ax1, ay1, ax2, ay2);
        float acx = (ax1 + ax2) * 0.5f, acy = (ay1 + ay2) * 0.5f;
        float aw = ax2 - ax1, ah = ay2 - ay1;
        int a = n % NA_T, hw = n / NA_T;
        const float* pb = pred + (size_t)b * 36 * NPOS;
        float dx = pb[(4 * a + 0) * NPOS + hw];
        float dy = pb[(4 * a + 1) * NPOS + hw];
        float dw = pb[(4 * a + 2) * NPOS + hw];
        float dh = pb[(4 * a + 3) * NPOS + hw];
        float px = acx + dx * aw, py = acy + dy * ah;
        float pw = aw * expf(dw), ph = ah * expf(dh);
        float x1 = px - 0.5f * pw, y1 = py - 0.5f * ph;
        float x2 = px + 0.5f * pw, y2 = py + 0.5f * ph;
        x1 = fminf(fmaxf(x1, 0.0f), 799.0f);
        y1 = fminf(fmaxf(y1, 0.0f), 799.0f);
        x2 = fminf(fmaxf(x2, 0.0f), 799.0f);
        y2 = fminf(fmaxf(y2, 0.0f), 799.0f);
        ((float4*)topb)[(size_t)b * PRE + i] = make_float4(x1, y1, x2, y2);
    }
}

// ---------------- k_nms: on-the-fly greedy NMS, no mask matrix ----------------

__global__ void __launch_bounds__(1024) k_nms(const float* __restrict__ topb,
                                              float* __restrict__ out) {
    int b = blockIdx.x, tid = threadIdx.x;
    int lane = tid & 63, wid = tid >> 6;
    __shared__ float4 boxes[2048];
    __shared__ float4 accb[POST];
    __shared__ u64 Smat[64];
    __shared__ u64 wsup[16];
    __shared__ int s_scount;

    for (int i = tid; i < 2048; i += 1024)
        boxes[i] = (i < PRE) ? ((const float4*)topb)[(size_t)b * PRE + i]
                             : make_float4(0.f, 0.f, 0.f, 0.f);
    if (tid == 0) s_scount = 0;
    __syncthreads();

    for (int c = 0; c < 32; ++c) {
        int A = s_scount;
        int base = c * 64;
        float4 cb = boxes[base + lane];
        // 1) suppressed-by-accepted: 16 waves split the accepted list
        bool sup = false;
        for (int a = wid; a < A; a += 16) {
            float4 ab = accb[a];
            sup |= iou_f(ab.x, ab.y, ab.z, ab.w, cb.x, cb.y, cb.z, cb.w) > 0.7f;
        }
        u64 bal = __ballot(sup);
        if (lane == 0) wsup[wid] = bal;
        // 2) intra-chunk 64x64 suppression matrix (wave w builds rows w*4..w*4+3)
        #pragma unroll
        for (int q = 0; q < 4; ++q) {
            int o = wid * 4 + q;
            float4 ob = boxes[base + o];
            bool hit = iou_f(ob.x, ob.y, ob.z, ob.w, cb.x, cb.y, cb.z, cb.w) > 0.7f;
            u64 m = __ballot(hit);
            if (lane == 0) Smat[o] = m;
        }
        __syncthreads();
        // 3) wave-0 bit-ops scan
        if (wid == 0) {
            u64 supmask = 0;
            #pragma unroll
            for (int i2 = 0; i2 < 16; ++i2) supmask |= wsup[i2];
            int jmax = min(64, PRE - base);
            u64 valid = (jmax >= 64) ? ~0ull : ((1ull << jmax) - 1ull);
            u64 live = (~supmask) & valid;
            int count = A;
            while (live && count < POST) {
                int i = __ffsll((long long)live) - 1;
                if (lane == 0) accb[count] = boxes[base + i];
                u64 sm = Smat[i];
                live &= ~sm;
                live &= ~(1ull << i);
                count++;
            }
            if (lane == 0) s_scount = count;
        }
        __syncthreads();
        if (s_scount >= POST) break;
    }
    int cntk = s_scount;
    for (int s = tid; s < POST; s += 1024) {
        float4 v = make_float4(0.f, 0.f, 0.f, 0.f);
        if (s < cntk) {
            float4 p = accb[s];
            v = make_float4(floorf(p.x), floorf(p.y), floorf(p.z), floorf(p.w));
        }
        ((float4*)out)[(size_t)b * POST + s] = v;
    }
}

// ---------------- k_sample (round-5 proven): tags -> counts -> selects -> loss ----------------

__global__ void __launch_bounds__(1024) k_sample(const int* __restrict__ labels,
                                                 const int* __restrict__ argmax_b,
                                                 const int* __restrict__ gt_best,
                                                 const u32* __restrict__ mant_g,
                                                 const float* __restrict__ pred,
                                                 const float* __restrict__ cls,
                                                 const float* __restrict__ gt,
                                                 double* __restrict__ acc,
                                                 int* __restrict__ cnt_out) {
    int b = blockIdx.x, tid = threadIdx.x;
    __shared__ unsigned char tag[22528];   // 0 neg, 1 pos, 2 ignore
    __shared__ u32 bitmap[704];            // gt_best membership
    __shared__ u64 sred[16];
    __shared__ u32 hist[2048];
    __shared__ u32 s_out[2];
    if (tid < 2) s_out[tid] = 0;

    for (int i = tid; i < 704; i += 1024) bitmap[i] = 0;
    __syncthreads();
    if (tid < NG) {
        int gn = gt_best[b * NG + tid];
        atomicOr(&bitmap[gn >> 5], 1u << (gn & 31));
    }
    __syncthreads();

    u32 cp = 0, cn = 0;
    #pragma unroll
    for (int c = 0; c < 22; ++c) {
        int n = tid + c * 1024;
        if (n < N_ANCH) {
            int enc = labels[(size_t)b * N_ANCH + n];
            int l = (enc == -2) ? -1 : (((bitmap[n >> 5] >> (n & 31)) & 1u) ? 1 : enc);
            tag[n] = (unsigned char)((l == 1) ? 1 : ((l == 0) ? 0 : 2));
            cp += (l == 1); cn += (l == 0);
        }
    }
    __syncthreads();
    u64 packed = block_sum_u64(((u64)cp << 32) | (u64)cn, sred, 16);
    int cpt = (int)(packed >> 32), ctot = (int)(packed & 0xffffffffu);
    int np = min(cpt, 128), nn = min(ctot, 256 - np);
    const u32* mg = mant_g + (size_t)b * N_ANCH;

    // radix select thresholds over 38-bit keys (mant<<15)|n: digits 11,9,9,9
    u64 Tp = ~0ull, Tn = ~0ull;
    for (int which = 0; which < 2; ++which) {
        bool need = which ? (ctot > nn) : (cpt > np);
        if (!need) continue;   // block-uniform
        unsigned char wtag = which ? (unsigned char)0 : (unsigned char)1;
        u32 rem = which ? (u32)nn : (u32)np;
        u64 pref = 0;
        for (int p = 0; p < 4; ++p) {
            int sh = (p == 0) ? 27 : (27 - 9 * p);   // 27,18,9,0
            int bitsp = (p == 0) ? 11 : 9;
            int nb = 1 << bitsp;
            for (int i = tid; i < nb; i += 1024) hist[i] = 0;
            __syncthreads();
            u64 himask = ~((1ull << (sh + bitsp)) - 1);
            #pragma unroll
            for (int c = 0; c < 22; ++c) {
                int n = tid + c * 1024;
                if (n < N_ANCH && tag[n] == wtag) {
                    u64 kk = (((u64)mg[n]) << 15) | (u32)n;
                    if ((kk & himask) == pref)
                        atomicAdd(&hist[(u32)((kk >> sh) & (u64)(nb - 1))], 1u);
                }
            }
            __syncthreads();
            hist_pick(hist, nb, rem, s_out);
            pref |= ((u64)s_out[0]) << sh;
            rem = s_out[1];
            __syncthreads();
        }
        if (which == 0) Tp = pref; else Tn = pref;
    }

    // loss over selected samples
    double lcls = 0.0, lbox = 0.0;
    #pragma unroll
    for (int c = 0; c < 22; ++c) {
        int n = tid + c * 1024;
        if (n >= N_ANCH) continue;
        unsigned char tg = tag[n];
        if (tg > 1) continue;
        u64 kk = (((u64)mg[n]) << 15) | (u32)n;
        int lab = -1;
        if (tg == 1) { if (kk <= Tp) lab = 1; }
        else         { if (kk <= Tn) lab = 0; }
        if (lab < 0) continue;
        int a = n % NA_T, hw = n / NA_T;
        float l0 = cls[((size_t)b * 18 + 2 * a + 0) * NPOS + hw];
        float l1 = cls[((size_t)b * 18 + 2 * a + 1) * NPOS + hw];
        float m = fmaxf(l0, l1);
        float s0 = l0 - m, s1 = l1 - m;
        float lse = logf(expf(s0) + expf(s1));
        lcls += (double)(-((lab ? s1 : s0) - lse));
        if (lab == 1) {
            const float* pb = pred + (size_t)b * 36 * NPOS;
            float dx = pb[(4 * a + 0) * NPOS + hw];
            float dy = pb[(4 * a + 1) * NPOS + hw];
            float dw = pb[(4 * a + 2) * NPOS + hw];
            float dh = pb[(4 * a + 3) * NPOS + hw];
            float ax1, ay1, ax2, ay2; anchor_corners(n, ax1, ay1, ax2, ay2);
            float acx = (ax1 + ax2) * 0.5f, acy = (ay1 + ay2) * 0.5f;
            float aw = ax2 - ax1, ah = ay2 - ay1;
            float4 G = ((const float4*)gt)[b * NG + argmax_b[(size_t)b * N_ANCH + n]];
            float gcx = (G.x + G.z) * 0.5f, gcy = (G.y + G.w) * 0.5f;
            float gw = G.z - G.x, gh = G.w - G.y;
            float t0 = (gcx - acx) / aw, t1 = (gcy - acy) / ah;
            float t2 = logf(gw / aw), t3 = logf(gh / ah);
            lbox += (double)(smooth_l1(dx - t0) + smooth_l1(dy - t1) +
                             smooth_l1(dw - t2) + smooth_l1(dh - t3));
        }
    }
    for (int o = 32; o >= 1; o >>= 1) {
        lcls += __shfl_down(lcls, o);
        lbox += __shfl_down(lbox, o);
    }
    if ((tid & 63) == 0) {
        atomicAdd(&acc[0], lcls);
        atomicAdd(&acc[1], lbox);
    }
    if (tid == 0) cnt_out[b] = np + nn;
}

__global__ void k_final(const double* __restrict__ acc, const int* __restrict__ cnt_out,
                        float* __restrict__ out) {
    if (threadIdx.x != 0 || blockIdx.x != 0) return;
    int total = 0, count0 = 0;
    for (int b = 0; b < BN; ++b) {
        total += cnt_out[b];
        if (b == 0) count0 = cnt_out[b];
    }
    out[BN * POST * 4 + 0] = (float)(acc[1] / (double)max(count0, 1));  // bbox_loss
    out[BN * POST * 4 + 1] = (float)(acc[0] / (double)max(total, 1));   // cls_loss
}

// ---------------- launch ----------------

extern "C" void kernel_launch(void* const* d_in, const int* in_sizes, int n_in,
                              void* d_out, int out_size, void* d_ws, size_t ws_size,
                              hipStream_t stream) {
    (void)in_sizes; (void)n_in; (void)out_size; (void)ws_size;
    const float* pred = (const float*)d_in[0];   // (8,36,50,50)
    const float* cls  = (const float*)d_in[1];   // (8,18,50,50)
    const float* gt   = (const float*)d_in[2];   // (8,20,4)
    float* out = (float*)d_out;                  // 9600 boxes + 2 losses

    char* w = (char*)d_ws;
    size_t off = 0;
    auto take = [&](size_t bytes) { void* p = w + off; off += (bytes + 255) & ~(size_t)255; return p; };
    u32* kd_g    = (u32*)take((size_t)TOTAL * 4);          // 720 KB
    u32* mant_g  = (u32*)take((size_t)TOTAL * 4);          // 720 KB
    int* labels  = (int*)take((size_t)TOTAL * 4);          // 720 KB
    int* argmax_b= (int*)take((size_t)TOTAL * 4);          // 720 KB
    float* topb  = (float*)take((size_t)BN * PRE * 4 * 4); // 256 KB
    int* gt_best = (int*)take((size_t)BN * NG * 4);
    int* cnt_out = (int*)take(BN * 4);
    double* acc  = (double*)take(2 * 8);

    k_front<<<NB_PROP + NB_LAB + NB_GTB, 256, 0, stream>>>(cls, gt, kd_g, mant_g,
                                                           labels, argmax_b, gt_best, acc);
    k_topk<<<BN, 1024, 0, stream>>>(kd_g, pred, topb);
    k_nms<<<BN, 1024, 0, stream>>>(topb, out);
    k_sample<<<BN, 1024, 0, stream>>>(labels, argmax_b, gt_best, mant_g, pred, cls, gt,
                                      acc, cnt_out);
    k_final<<<1, 64, 0, stream>>>(acc, cnt_out, out);
}

// Round 9
// 218.288 us; speedup vs baseline: 3.7503x; 1.2461x over previous
//
#include <hip/hip_runtime.h>
#include <math.h>

typedef unsigned long long u64;
typedef unsigned int u32;

#define BN 8
#define NA_T 9
#define NPOS 2500
#define FHW 50
#define N_ANCH 22500
#define NG 20
#define PRE 2000
#define POST 300
#define TOTAL (BN * N_ANCH)      // 180000
#define HALF_RNG 90000u
#define SELCAP 2048

// grid partition for k_front
#define NB_PROP 704   // ceil(180000/256)
#define NB_LAB  704   // 88 * 8
#define NB_GTB  160   // 8 * 20

// ---------------- device helpers ----------------

__device__ __forceinline__ void anchor_dims(int d, float& w, float& h) {
    const double scl[3] = {8.0, 16.0, 32.0};
    const double rat[3] = {0.5, 1.0, 2.0};
    double s = 16.0 * scl[d / 3];
    double r = rat[d % 3];
    w = (float)(s * sqrt(r));
    h = (float)(s * sqrt(1.0 / r));
}

__device__ __forceinline__ void anchor_corners(int n, float& x1, float& y1, float& x2, float& y2) {
    int d = n / NPOS, k = n % NPOS;
    float cx = (float)(8 + 16 * (k / FHW));
    float cy = (float)(8 + 16 * (k % FHW));
    float w, h; anchor_dims(d, w, h);
    x1 = cx - 0.5f * w; y1 = cy - 0.5f * h;
    x2 = cx + 0.5f * w; y2 = cy + 0.5f * h;
}

__device__ __forceinline__ float iou_f(float ax1, float ay1, float ax2, float ay2,
                                       float bx1, float by1, float bx2, float by2) {
    float tlx = fmaxf(ax1, bx1), tly = fmaxf(ay1, by1);
    float brx = fminf(ax2, bx2), bry = fminf(ay2, by2);
    float wx = fmaxf(brx - tlx, 0.0f);
    float wy = fmaxf(bry - tly, 0.0f);
    float inter = wx * wy;
    float a1 = (ax2 - ax1) * (ay2 - ay1);
    float a2 = (bx2 - bx1) * (by2 - by1);
    float den = fmaxf(a1 + a2 - inter, 1e-8f);
    return inter / den;
}

__device__ __forceinline__ unsigned int f32_sort_asc(float f) {
    unsigned int u = __float_as_uint(f);
    return (u & 0x80000000u) ? ~u : (u | 0x80000000u);
}

#define TF_R(r) { x0 += x1; x1 = ((x1 << r) | (x1 >> (32 - r))); x1 ^= x0; }
__device__ __forceinline__ unsigned int threefry_bits(unsigned int j) {
    unsigned int i = (j < HALF_RNG) ? j : j - HALF_RNG;
    unsigned int x0 = i, x1 = i + HALF_RNG;
    const unsigned int ks0 = 0u, ks1 = 42u, ks2 = 0x1BD11BDAu ^ 0u ^ 42u;
    x0 += ks0; x1 += ks1;
    TF_R(13) TF_R(15) TF_R(26) TF_R(6)
    x0 += ks1; x1 += ks2 + 1u;
    TF_R(17) TF_R(29) TF_R(16) TF_R(24)
    x0 += ks2; x1 += ks0 + 2u;
    TF_R(13) TF_R(15) TF_R(26) TF_R(6)
    x0 += ks0; x1 += ks1 + 3u;
    TF_R(17) TF_R(29) TF_R(16) TF_R(24)
    x0 += ks1; x1 += ks2 + 4u;
    TF_R(13) TF_R(15) TF_R(26) TF_R(6)
    x0 += ks2; x1 += ks0 + 5u;
    return (j < HALF_RNG) ? x0 : x1;
}

__device__ __forceinline__ float smooth_l1(float d) {
    float ad = fabsf(d);
    return (ad < (float)(1.0 / 9.0)) ? (4.5f * d) * d : (ad - (float)(0.5 / 9.0));
}

// block-wide u64 sum broadcast. sred has 16 slots (nwaves<=16).
__device__ __forceinline__ u64 block_sum_u64(u64 v, u64* sred, int nwaves) {
    for (int o = 32; o >= 1; o >>= 1) v += __shfl_down(v, o);
    int wid = threadIdx.x >> 6;
    if ((threadIdx.x & 63) == 0) sred[wid] = v;
    __syncthreads();
    u64 s = 0;
    for (int i = 0; i < nwaves; ++i) s += sred[i];
    return s;
}

// After hist[0..nb) filled: find bin containing rank `remaining` (1-indexed) and
// residual rank. Wave 0 computes; result in s_out[0]=digit, s_out[1]=remaining.
// All threads call (barrier inside). nb multiple of 64.
__device__ __forceinline__ void hist_pick(const u32* hist, int nb,
                                          u32 remaining, u32* s_out) {
    if (threadIdx.x < 64) {
        int lane = threadIdx.x;
        int bpl = nb >> 6;
        int base = lane * bpl;
        u32 s = 0;
        for (int i = 0; i < bpl; ++i) s += hist[base + i];
        u32 p = s;
        for (int o = 1; o < 64; o <<= 1) {
            u32 t = __shfl_up(p, o);
            if (lane >= o) p += t;
        }
        u32 e = p - s;
        if (e < remaining && remaining <= p) {
            u32 cum = e;
            for (int i = 0; i < bpl; ++i) {
                u32 h = hist[base + i];
                if (cum + h >= remaining) {
                    s_out[0] = (u32)(base + i);
                    s_out[1] = remaining - cum;
                    break;
                }
                cum += h;
            }
        }
    }
    __syncthreads();
}

// ---------------- k_front: keys+mant | labels(enc)+argmax | gtbest ----------------

__global__ void k_front(const float* __restrict__ cls, const float* __restrict__ gt,
                        u32* __restrict__ kd_g, u32* __restrict__ mant_g,
                        int* __restrict__ labels, int* __restrict__ argmax_b,
                        int* __restrict__ gt_best, double* __restrict__ acc,
                        u32* __restrict__ done) {
    int bid = blockIdx.x;
    if (bid == 0) {
        if (threadIdx.x < 2) acc[threadIdx.x] = 0.0;
        if (threadIdx.x == 2) *done = 0;
    }

    if (bid < NB_PROP) {
        int t = bid * 256 + threadIdx.x;
        if (t >= TOTAL) return;
        int b = t / N_ANCH, n = t % N_ANCH;
        int a = n % NA_T, hw = n / NA_T;
        float score = cls[((size_t)b * 18 + 9 + a) * NPOS + hw];
        kd_g[t] = ~f32_sort_asc(score);                    // asc (kd<<15|n) == lax.top_k order
        mant_g[t] = threefry_bits((unsigned int)t) >> 9;   // jax uniform mantissa bits
    } else if (bid < NB_PROP + NB_LAB) {
        __shared__ float4 g[NG];
        int lb = bid - NB_PROP;
        int b = lb / 88, bx = lb % 88;
        if (threadIdx.x < NG) g[threadIdx.x] = ((const float4*)gt)[b * NG + threadIdx.x];
        __syncthreads();
        int n = bx * 256 + threadIdx.x;
        if (n >= N_ANCH) return;
        float ax1, ay1, ax2, ay2; anchor_corners(n, ax1, ay1, ax2, ay2);
        float best = -1.0f; int bi = 0;
        for (int gi = 0; gi < NG; ++gi) {
            float4 G = g[gi];
            float v = iou_f(G.x, G.y, G.z, G.w, ax1, ay1, ax2, ay2);
            if (v > best) { best = v; bi = gi; }  // first-max
        }
        int lab = -1;
        if (best < 0.3f) lab = 0;
        if (best >= 0.7f) lab = 1;
        // inside anchors forced to -1 LAST in reference; encode -2 so the
        // gt_best->1 override is known not to apply there.
        bool inside = (ax1 >= 0.0f && ay1 >= 0.0f && ax2 <= 800.0f && ay2 <= 800.0f);
        labels[b * N_ANCH + n] = inside ? -2 : lab;
        argmax_b[b * N_ANCH + n] = bi;
    } else {
        int gid = bid - NB_PROP - NB_LAB;
        int b = gid / NG, gi = gid % NG;
        float4 G = ((const float4*)gt)[b * NG + gi];
        float best = -1.0f; int bidx = N_ANCH;
        for (int d = 0; d < 9; ++d) {
            float w, h; anchor_dims(d, w, h);   // hoisted double-sqrt per d
            for (int k = threadIdx.x; k < NPOS; k += 256) {
                float cx = (float)(8 + 16 * (k / FHW));
                float cy = (float)(8 + 16 * (k % FHW));
                float x1 = cx - 0.5f * w, y1 = cy - 0.5f * h;
                float x2 = cx + 0.5f * w, y2 = cy + 0.5f * h;
                float v = iou_f(G.x, G.y, G.z, G.w, x1, y1, x2, y2);
                if (v > best) { best = v; bidx = d * NPOS + k; }  // ascending n per thread
            }
        }
        __shared__ float sv[256]; __shared__ int si[256];
        sv[threadIdx.x] = best; si[threadIdx.x] = bidx;
        __syncthreads();
        for (int s = 128; s > 0; s >>= 1) {
            if (threadIdx.x < s) {
                float v2 = sv[threadIdx.x + s]; int i2 = si[threadIdx.x + s];
                if (v2 > sv[threadIdx.x] || (v2 == sv[threadIdx.x] && i2 < si[threadIdx.x])) {
                    sv[threadIdx.x] = v2; si[threadIdx.x] = i2;
                }
            }
            __syncthreads();
        }
        if (threadIdx.x == 0) gt_best[gid] = si[0];
    }
}

// ---------------- k_mid: blocks 0-7 topk+NMS | blocks 8-15 sample+loss+final ----------------

__global__ void __launch_bounds__(1024) k_mid(
    const u32* __restrict__ kd_g, const u32* __restrict__ mant_g,
    const int* __restrict__ labels, const int* __restrict__ argmax_b,
    const int* __restrict__ gt_best, const float* __restrict__ pred,
    const float* __restrict__ cls, const float* __restrict__ gt,
    float* __restrict__ out, double* __restrict__ acc,
    int* __restrict__ cnt_out, u32* __restrict__ done)
{
    int tid = threadIdx.x;
    int lane = tid & 63, wid = tid >> 6;

    __shared__ u32 histA[4096];     // topk hist / sample hist (2048 used)
    __shared__ u64 poolB[2048];     // topk boundary buf, then (x1,y1) | sample: bitmap + sred
    __shared__ u64 sk[2048];        // topk keys/sort, then (x2,y2)
    __shared__ float4 accb[POST];   // NMS accepted boxes
    __shared__ u64 Smat[64];
    __shared__ u64 wsup[16];
    __shared__ u32 s_out[2];
    __shared__ u32 s_cnt;
    __shared__ int s_scount;
    if (tid < 2) s_out[tid] = 0;

    if (blockIdx.x < BN) {
        // ================== TOPK + NMS (batch b) ==================
        int b = blockIdx.x;
        const u32* kb = kd_g + (size_t)b * N_ANCH;

        // ---- 2-level radix select of 2000th-smallest 47-bit key ----
        u64 prefix = 0; u32 remaining = PRE; int bufcnt = -1;
        for (int p = 0; p < 4; ++p) {
            int sh = (p < 3) ? (35 - 12 * p) : 0;
            int bitsp = (p < 3) ? 12 : 11;
            int nb = 1 << bitsp;
            for (int i = tid; i < nb; i += 1024) histA[i] = 0;
            __syncthreads();
            u64 himask = ~((1ull << (sh + bitsp)) - 1);
            if (bufcnt < 0) {
                #pragma unroll
                for (int c = 0; c < 22; ++c) {
                    int n = tid + c * 1024;
                    if (n < N_ANCH) {
                        u64 kk = (((u64)kb[n]) << 15) | (u32)n;
                        if ((kk & himask) == prefix)
                            atomicAdd(&histA[(u32)((kk >> sh) & (u64)(nb - 1))], 1u);
                    }
                }
            } else {
                for (int i = tid; i < bufcnt; i += 1024) {
                    u64 kk = poolB[i];
                    if ((kk & himask) == prefix)
                        atomicAdd(&histA[(u32)((kk >> sh) & (u64)(nb - 1))], 1u);
                }
            }
            __syncthreads();
            hist_pick(histA, nb, remaining, s_out);
            u32 dig = s_out[0]; remaining = s_out[1];
            u32 bincnt = histA[dig];
            prefix |= ((u64)dig) << sh;
            __syncthreads();
            if (bufcnt < 0 && p < 3 && bincnt <= SELCAP) {
                if (tid == 0) s_cnt = 0;
                __syncthreads();
                u64 pmask = ~((1ull << sh) - 1);
                #pragma unroll
                for (int c = 0; c < 22; ++c) {
                    int n = tid + c * 1024;
                    if (n < N_ANCH) {
                        u64 kk = (((u64)kb[n]) << 15) | (u32)n;
                        if ((kk & pmask) == prefix) { u32 pos = atomicAdd(&s_cnt, 1u); poolB[pos] = kk; }
                    }
                }
                __syncthreads();
                bufcnt = (int)s_cnt;
            }
        }
        u64 T = prefix;   // exact: {key <= T} has size 2000

        // compact selected keys, bitonic sort 2048 in LDS
        if (tid == 0) s_cnt = 0;
        for (int i = tid; i < 2048; i += 1024) sk[i] = ~0ull;
        __syncthreads();
        #pragma unroll
        for (int c = 0; c < 22; ++c) {
            int n = tid + c * 1024;
            if (n < N_ANCH) {
                u64 kk = (((u64)kb[n]) << 15) | (u32)n;
                if (kk <= T) { u32 pp = atomicAdd(&s_cnt, 1u); sk[pp] = kk; }
            }
        }
        __syncthreads();
        for (int k = 2; k <= 2048; k <<= 1) {
            for (int j = k >> 1; j > 0; j >>= 1) {
                for (int i = tid; i < 2048; i += 1024) {
                    int l = i ^ j;
                    if (l > i) {
                        u64 ai = sk[i], al = sk[l];
                        bool up = ((i & k) == 0);
                        if ((ai > al) == up) { sk[i] = al; sk[l] = ai; }
                    }
                }
                __syncthreads();
            }
        }

        // recompute proposal boxes for the sorted 2000 (bit-identical math):
        // (x1,y1) -> poolB[i] as float2, (x2,y2) -> sk[i] as float2 (key read first)
        float2* bl = (float2*)poolB;
        float2* bh = (float2*)sk;
        for (int i = tid; i < 2048; i += 1024) {
            float2 lo = make_float2(0.f, 0.f), hi = make_float2(0.f, 0.f);
            if (i < PRE) {
                int n = (int)(sk[i] & 0x7fffu);
                float ax1, ay1, ax2, ay2; anchor_corners(n, ax1, ay1, ax2, ay2);
                float acx = (ax1 + ax2) * 0.5f, acy = (ay1 + ay2) * 0.5f;
                float aw = ax2 - ax1, ah = ay2 - ay1;
                int a = n % NA_T, hw = n / NA_T;
                const float* pb = pred + (size_t)b * 36 * NPOS;
                float dx = pb[(4 * a + 0) * NPOS + hw];
                float dy = pb[(4 * a + 1) * NPOS + hw];
                float dw = pb[(4 * a + 2) * NPOS + hw];
                float dh = pb[(4 * a + 3) * NPOS + hw];
                float px = acx + dx * aw, py = acy + dy * ah;
                float pw = aw * expf(dw), ph = ah * expf(dh);
                float x1 = px - 0.5f * pw, y1 = py - 0.5f * ph;
                float x2 = px + 0.5f * pw, y2 = py + 0.5f * ph;
                x1 = fminf(fmaxf(x1, 0.0f), 799.0f);
                y1 = fminf(fmaxf(y1, 0.0f), 799.0f);
                x2 = fminf(fmaxf(x2, 0.0f), 799.0f);
                y2 = fminf(fmaxf(y2, 0.0f), 799.0f);
                lo = make_float2(x1, y1); hi = make_float2(x2, y2);
            }
            bl[i] = lo; bh[i] = hi;
        }
        if (tid == 0) s_scount = 0;
        __syncthreads();

        // ---- on-the-fly greedy NMS ----
        for (int c = 0; c < 32; ++c) {
            int A = s_scount;
            int base = c * 64;
            float2 clo = bl[base + lane], chi = bh[base + lane];
            // 1) suppressed-by-accepted: 16 waves split the accepted list
            bool sup = false;
            for (int a = wid; a < A; a += 16) {
                float4 ab = accb[a];
                sup |= iou_f(ab.x, ab.y, ab.z, ab.w, clo.x, clo.y, chi.x, chi.y) > 0.7f;
            }
            u64 bal = __ballot(sup);
            if (lane == 0) wsup[wid] = bal;
            // 2) intra-chunk 64x64 suppression matrix
            #pragma unroll
            for (int q = 0; q < 4; ++q) {
                int o = wid * 4 + q;
                float2 olo = bl[base + o], ohi = bh[base + o];
                bool hit = iou_f(olo.x, olo.y, ohi.x, ohi.y, clo.x, clo.y, chi.x, chi.y) > 0.7f;
                u64 m = __ballot(hit);
                if (lane == 0) Smat[o] = m;
            }
            __syncthreads();
            // 3) wave-0 bit-ops scan
            if (wid == 0) {
                u64 supmask = 0;
                #pragma unroll
                for (int i2 = 0; i2 < 16; ++i2) supmask |= wsup[i2];
                int jmax = min(64, PRE - base);
                u64 valid = (jmax >= 64) ? ~0ull : ((1ull << jmax) - 1ull);
                u64 live = (~supmask) & valid;
                int count = A;
                while (live && count < POST) {
                    int i = __ffsll((long long)live) - 1;
                    if (lane == 0) {
                        float2 lo2 = bl[base + i], hi2 = bh[base + i];
                        accb[count] = make_float4(lo2.x, lo2.y, hi2.x, hi2.y);
                    }
                    u64 sm = Smat[i];
                    live &= ~sm;
                    live &= ~(1ull << i);
                    count++;
                }
                if (lane == 0) s_scount = count;
            }
            __syncthreads();
            if (s_scount >= POST) break;
        }
        int cntk = s_scount;
        for (int s = tid; s < POST; s += 1024) {
            float4 v = make_float4(0.f, 0.f, 0.f, 0.f);
            if (s < cntk) {
                float4 p = accb[s];
                v = make_float4(floorf(p.x), floorf(p.y), floorf(p.z), floorf(p.w));
            }
            ((float4*)out)[(size_t)b * POST + s] = v;
        }
    } else {
        // ================== SAMPLE + LOSS (batch b) ==================
        int b = blockIdx.x - BN;
        u32* bitmap = (u32*)poolB;        // 704 u32 = 2816 B
        u64* sred   = poolB + 512;        // byte offset 4096, clear of bitmap
        u32* hist   = histA;              // 2048 bins used

        for (int i = tid; i < 704; i += 1024) bitmap[i] = 0;
        __syncthreads();
        if (tid < NG) {
            int gn = gt_best[b * NG + tid];
            atomicOr(&bitmap[gn >> 5], 1u << (gn & 31));
        }
        __syncthreads();

        const int* lb = labels + (size_t)b * N_ANCH;
        u32 cp = 0, cn = 0;
        #pragma unroll
        for (int c = 0; c < 22; ++c) {
            int n = tid + c * 1024;
            if (n < N_ANCH) {
                int enc = lb[n];
                int l = (enc == -2) ? -1 : (((bitmap[n >> 5] >> (n & 31)) & 1u) ? 1 : enc);
                cp += (l == 1); cn += (l == 0);
            }
        }
        __syncthreads();
        u64 packed = block_sum_u64(((u64)cp << 32) | (u64)cn, sred, 16);
        int cpt = (int)(packed >> 32), ctot = (int)(packed & 0xffffffffu);
        int np = min(cpt, 128), nn = min(ctot, 256 - np);
        const u32* mg = mant_g + (size_t)b * N_ANCH;

        // radix select thresholds over 38-bit keys (mant<<15)|n: digits 11,9,9,9
        u64 Tp = ~0ull, Tn = ~0ull;
        for (int which = 0; which < 2; ++which) {
            bool need = which ? (ctot > nn) : (cpt > np);
            if (!need) continue;   // block-uniform
            int wl = which ? 0 : 1;
            u32 rem = which ? (u32)nn : (u32)np;
            u64 pref = 0;
            for (int p = 0; p < 4; ++p) {
                int sh = (p == 0) ? 27 : (27 - 9 * p);   // 27,18,9,0
                int bitsp = (p == 0) ? 11 : 9;
                int nb = 1 << bitsp;
                for (int i = tid; i < nb; i += 1024) hist[i] = 0;
                __syncthreads();
                u64 himask = ~((1ull << (sh + bitsp)) - 1);
                #pragma unroll
                for (int c = 0; c < 22; ++c) {
                    int n = tid + c * 1024;
                    if (n < N_ANCH) {
                        int enc = lb[n];
                        int l = (enc == -2) ? -1 : (((bitmap[n >> 5] >> (n & 31)) & 1u) ? 1 : enc);
                        if (l == wl) {
                            u64 kk = (((u64)mg[n]) << 15) | (u32)n;
                            if ((kk & himask) == pref)
                                atomicAdd(&hist[(u32)((kk >> sh) & (u64)(nb - 1))], 1u);
                        }
                    }
                }
                __syncthreads();
                hist_pick(hist, nb, rem, s_out);
                pref |= ((u64)s_out[0]) << sh;
                rem = s_out[1];
                __syncthreads();
            }
            if (which == 0) Tp = pref; else Tn = pref;
        }

        // loss over selected samples
        double lcls = 0.0, lbox = 0.0;
        #pragma unroll
        for (int c = 0; c < 22; ++c) {
            int n = tid + c * 1024;
            if (n >= N_ANCH) continue;
            int enc = lb[n];
            int l = (enc == -2) ? -1 : (((bitmap[n >> 5] >> (n & 31)) & 1u) ? 1 : enc);
            if (l < 0) continue;
            u64 kk = (((u64)mg[n]) << 15) | (u32)n;
            int lab = -1;
            if (l == 1) { if (kk <= Tp) lab = 1; }
            else        { if (kk <= Tn) lab = 0; }
            if (lab < 0) continue;
            int a = n % NA_T, hw = n / NA_T;
            float l0 = cls[((size_t)b * 18 + 2 * a + 0) * NPOS + hw];
            float l1 = cls[((size_t)b * 18 + 2 * a + 1) * NPOS + hw];
            float m = fmaxf(l0, l1);
            float s0 = l0 - m, s1 = l1 - m;
            float lse = logf(expf(s0) + expf(s1));
            lcls += (double)(-((lab ? s1 : s0) - lse));
            if (lab == 1) {
                const float* pb = pred + (size_t)b * 36 * NPOS;
                float dx = pb[(4 * a + 0) * NPOS + hw];
                float dy = pb[(4 * a + 1) * NPOS + hw];
                float dw = pb[(4 * a + 2) * NPOS + hw];
                float dh = pb[(4 * a + 3) * NPOS + hw];
                float ax1, ay1, ax2, ay2; anchor_corners(n, ax1, ay1, ax2, ay2);
                float acx = (ax1 + ax2) * 0.5f, acy = (ay1 + ay2) * 0.5f;
                float aw = ax2 - ax1, ah = ay2 - ay1;
                float4 G = ((const float4*)gt)[b * NG + argmax_b[(size_t)b * N_ANCH + n]];
                float gcx = (G.x + G.z) * 0.5f, gcy = (G.y + G.w) * 0.5f;
                float gw = G.z - G.x, gh = G.w - G.y;
                float t0 = (gcx - acx) / aw, t1 = (gcy - acy) / ah;
                float t2 = logf(gw / aw), t3 = logf(gh / ah);
                lbox += (double)(smooth_l1(dx - t0) + smooth_l1(dy - t1) +
                                 smooth_l1(dw - t2) + smooth_l1(dh - t3));
            }
        }
        for (int o = 32; o >= 1; o >>= 1) {
            lcls += __shfl_down(lcls, o);
            lbox += __shfl_down(lbox, o);
        }
        if ((tid & 63) == 0) {
            atomicAdd(&acc[0], lcls);
            atomicAdd(&acc[1], lbox);
        }
        if (tid == 0) cnt_out[b] = np + nn;
        __syncthreads();

        // last sample block writes the two losses
        if (tid == 0) {
            __threadfence();
            u32 r = atomicAdd(done, 1u);
            if (r == BN - 1) {
                __threadfence();
                volatile double* va = (volatile double*)acc;
                volatile int* vc = (volatile int*)cnt_out;
                double a0 = va[0], a1 = va[1];
                int total = 0, c0 = 0;
                for (int bb = 0; bb < BN; ++bb) {
                    int v = vc[bb];
                    total += v;
                    if (bb == 0) c0 = v;
                }
                out[BN * POST * 4 + 0] = (float)(a1 / (double)max(c0, 1));     // bbox_loss
                out[BN * POST * 4 + 1] = (float)(a0 / (double)max(total, 1));  // cls_loss
            }
        }
    }
}

// ---------------- launch ----------------

extern "C" void kernel_launch(void* const* d_in, const int* in_sizes, int n_in,
                              void* d_out, int out_size, void* d_ws, size_t ws_size,
                              hipStream_t stream) {
    (void)in_sizes; (void)n_in; (void)out_size; (void)ws_size;
    const float* pred = (const float*)d_in[0];   // (8,36,50,50)
    const float* cls  = (const float*)d_in[1];   // (8,18,50,50)
    const float* gt   = (const float*)d_in[2];   // (8,20,4)
    float* out = (float*)d_out;                  // 9600 boxes + 2 losses

    char* w = (char*)d_ws;
    size_t off = 0;
    auto take = [&](size_t bytes) { void* p = w + off; off += (bytes + 255) & ~(size_t)255; return p; };
    u32* kd_g    = (u32*)take((size_t)TOTAL * 4);          // 720 KB
    u32* mant_g  = (u32*)take((size_t)TOTAL * 4);          // 720 KB
    int* labels  = (int*)take((size_t)TOTAL * 4);          // 720 KB
    int* argmax_b= (int*)take((size_t)TOTAL * 4);          // 720 KB
    int* gt_best = (int*)take((size_t)BN * NG * 4);
    int* cnt_out = (int*)take(BN * 4);
    double* acc  = (double*)take(2 * 8);
    u32* done    = (u32*)take(4);

    k_front<<<NB_PROP + NB_LAB + NB_GTB, 256, 0, stream>>>(cls, gt, kd_g, mant_g,
                                                           labels, argmax_b, gt_best,
                                                           acc, done);
    k_mid<<<2 * BN, 1024, 0, stream>>>(kd_g, mant_g, labels, argmax_b, gt_best,
                                       pred, cls, gt, out, acc, cnt_out, done);
}

// Round 12
// 217.220 us; speedup vs baseline: 3.7688x; 1.0049x over previous
//
#include <hip/hip_runtime.h>
#include <math.h>

typedef unsigned long long u64;
typedef unsigned int u32;

#define BN 8
#define NA_T 9
#define NPOS 2500
#define FHW 50
#define N_ANCH 22500
#define NG 20
#define PRE 2000
#define POST 300
#define TOTAL (BN * N_ANCH)      // 180000
#define HALF_RNG 90000u
#define SELCAP 2048

// grid partition for k_front
#define NB_PROP 704   // ceil(180000/256)
#define NB_LAB  704   // 88 * 8
#define NB_GTB  160   // 8 * 20

// ---------------- device helpers ----------------

__device__ __forceinline__ void anchor_dims(int d, float& w, float& h) {
    const double scl[3] = {8.0, 16.0, 32.0};
    const double rat[3] = {0.5, 1.0, 2.0};
    double s = 16.0 * scl[d / 3];
    double r = rat[d % 3];
    w = (float)(s * sqrt(r));
    h = (float)(s * sqrt(1.0 / r));
}

__device__ __forceinline__ void anchor_corners(int n, float& x1, float& y1, float& x2, float& y2) {
    int d = n / NPOS, k = n % NPOS;
    float cx = (float)(8 + 16 * (k / FHW));
    float cy = (float)(8 + 16 * (k % FHW));
    float w, h; anchor_dims(d, w, h);
    x1 = cx - 0.5f * w; y1 = cy - 0.5f * h;
    x2 = cx + 0.5f * w; y2 = cy + 0.5f * h;
}

__device__ __forceinline__ float iou_f(float ax1, float ay1, float ax2, float ay2,
                                       float bx1, float by1, float bx2, float by2) {
    float tlx = fmaxf(ax1, bx1), tly = fmaxf(ay1, by1);
    float brx = fminf(ax2, bx2), bry = fminf(ay2, by2);
    float wx = fmaxf(brx - tlx, 0.0f);
    float wy = fmaxf(bry - tly, 0.0f);
    float inter = wx * wy;
    float a1 = (ax2 - ax1) * (ay2 - ay1);
    float a2 = (bx2 - bx1) * (by2 - by1);
    float den = fmaxf(a1 + a2 - inter, 1e-8f);
    return inter / den;
}

__device__ __forceinline__ unsigned int f32_sort_asc(float f) {
    unsigned int u = __float_as_uint(f);
    return (u & 0x80000000u) ? ~u : (u | 0x80000000u);
}

#define TF_R(r) { x0 += x1; x1 = ((x1 << r) | (x1 >> (32 - r))); x1 ^= x0; }
__device__ __forceinline__ unsigned int threefry_bits(unsigned int j) {
    unsigned int i = (j < HALF_RNG) ? j : j - HALF_RNG;
    unsigned int x0 = i, x1 = i + HALF_RNG;
    const unsigned int ks0 = 0u, ks1 = 42u, ks2 = 0x1BD11BDAu ^ 0u ^ 42u;
    x0 += ks0; x1 += ks1;
    TF_R(13) TF_R(15) TF_R(26) TF_R(6)
    x0 += ks1; x1 += ks2 + 1u;
    TF_R(17) TF_R(29) TF_R(16) TF_R(24)
    x0 += ks2; x1 += ks0 + 2u;
    TF_R(13) TF_R(15) TF_R(26) TF_R(6)
    x0 += ks0; x1 += ks1 + 3u;
    TF_R(17) TF_R(29) TF_R(16) TF_R(24)
    x0 += ks1; x1 += ks2 + 4u;
    TF_R(13) TF_R(15) TF_R(26) TF_R(6)
    x0 += ks2; x1 += ks0 + 5u;
    return (j < HALF_RNG) ? x0 : x1;
}

__device__ __forceinline__ float smooth_l1(float d) {
    float ad = fabsf(d);
    return (ad < (float)(1.0 / 9.0)) ? (4.5f * d) * d : (ad - (float)(0.5 / 9.0));
}

// block-wide u64 sum broadcast. sred has 16 slots (nwaves<=16).
__device__ __forceinline__ u64 block_sum_u64(u64 v, u64* sred, int nwaves) {
    for (int o = 32; o >= 1; o >>= 1) v += __shfl_down(v, o);
    int wid = threadIdx.x >> 6;
    if ((threadIdx.x & 63) == 0) sred[wid] = v;
    __syncthreads();
    u64 s = 0;
    for (int i = 0; i < nwaves; ++i) s += sred[i];
    return s;
}

// After hist[0..nb) filled: find bin containing rank `remaining` (1-indexed) and
// residual rank. Wave 0 computes; result in s_out[0]=digit, s_out[1]=remaining.
// All threads call (barrier inside). nb multiple of 64.
__device__ __forceinline__ void hist_pick(const u32* hist, int nb,
                                          u32 remaining, u32* s_out) {
    if (threadIdx.x < 64) {
        int lane = threadIdx.x;
        int bpl = nb >> 6;
        int base = lane * bpl;
        u32 s = 0;
        for (int i = 0; i < bpl; ++i) s += hist[base + i];
        u32 p = s;
        for (int o = 1; o < 64; o <<= 1) {
            u32 t = __shfl_up(p, o);
            if (lane >= o) p += t;
        }
        u32 e = p - s;
        if (e < remaining && remaining <= p) {
            u32 cum = e;
            for (int i = 0; i < bpl; ++i) {
                u32 h = hist[base + i];
                if (cum + h >= remaining) {
                    s_out[0] = (u32)(base + i);
                    s_out[1] = remaining - cum;
                    break;
                }
                cum += h;
            }
        }
    }
    __syncthreads();
}

// ---------------- k_front: keys+mant | labels(enc)+argmax | gtbest ----------------

__global__ void k_front(const float* __restrict__ cls, const float* __restrict__ gt,
                        u32* __restrict__ kd_g, u32* __restrict__ mant_g,
                        int* __restrict__ labels, int* __restrict__ argmax_b,
                        int* __restrict__ gt_best, double* __restrict__ acc,
                        u32* __restrict__ done) {
    int bid = blockIdx.x;
    if (bid == 0) {
        if (threadIdx.x < 2) acc[threadIdx.x] = 0.0;
        if (threadIdx.x == 2) *done = 0;
    }

    if (bid < NB_PROP) {
        int t = bid * 256 + threadIdx.x;
        if (t >= TOTAL) return;
        int b = t / N_ANCH, n = t % N_ANCH;
        int a = n % NA_T, hw = n / NA_T;
        float score = cls[((size_t)b * 18 + 9 + a) * NPOS + hw];
        kd_g[t] = ~f32_sort_asc(score);                    // asc (kd<<15|n) == lax.top_k order
        mant_g[t] = threefry_bits((unsigned int)t) >> 9;   // jax uniform mantissa bits
    } else if (bid < NB_PROP + NB_LAB) {
        __shared__ float4 g[NG];
        int lb = bid - NB_PROP;
        int b = lb / 88, bx = lb % 88;
        if (threadIdx.x < NG) g[threadIdx.x] = ((const float4*)gt)[b * NG + threadIdx.x];
        __syncthreads();
        int n = bx * 256 + threadIdx.x;
        if (n >= N_ANCH) return;
        float ax1, ay1, ax2, ay2; anchor_corners(n, ax1, ay1, ax2, ay2);
        float best = -1.0f; int bi = 0;
        for (int gi = 0; gi < NG; ++gi) {
            float4 G = g[gi];
            float v = iou_f(G.x, G.y, G.z, G.w, ax1, ay1, ax2, ay2);
            if (v > best) { best = v; bi = gi; }  // first-max
        }
        int lab = -1;
        if (best < 0.3f) lab = 0;
        if (best >= 0.7f) lab = 1;
        // inside anchors forced to -1 LAST in reference; encode -2 so the
        // gt_best->1 override is known not to apply there.
        bool inside = (ax1 >= 0.0f && ay1 >= 0.0f && ax2 <= 800.0f && ay2 <= 800.0f);
        labels[b * N_ANCH + n] = inside ? -2 : lab;
        argmax_b[b * N_ANCH + n] = bi;
    } else {
        int gid = bid - NB_PROP - NB_LAB;
        int b = gid / NG, gi = gid % NG;
        float4 G = ((const float4*)gt)[b * NG + gi];
        float best = -1.0f; int bidx = N_ANCH;
        for (int d = 0; d < 9; ++d) {
            float w, h; anchor_dims(d, w, h);   // hoisted double-sqrt per d
            for (int k = threadIdx.x; k < NPOS; k += 256) {
                float cx = (float)(8 + 16 * (k / FHW));
                float cy = (float)(8 + 16 * (k % FHW));
                float x1 = cx - 0.5f * w, y1 = cy - 0.5f * h;
                float x2 = cx + 0.5f * w, y2 = cy + 0.5f * h;
                float v = iou_f(G.x, G.y, G.z, G.w, x1, y1, x2, y2);
                if (v > best) { best = v; bidx = d * NPOS + k; }  // ascending n per thread
            }
        }
        __shared__ float sv[256]; __shared__ int si[256];
        sv[threadIdx.x] = best; si[threadIdx.x] = bidx;
        __syncthreads();
        for (int s = 128; s > 0; s >>= 1) {
            if (threadIdx.x < s) {
                float v2 = sv[threadIdx.x + s]; int i2 = si[threadIdx.x + s];
                if (v2 > sv[threadIdx.x] || (v2 == sv[threadIdx.x] && i2 < si[threadIdx.x])) {
                    sv[threadIdx.x] = v2; si[threadIdx.x] = i2;
                }
            }
            __syncthreads();
        }
        if (threadIdx.x == 0) gt_best[gid] = si[0];
    }
}

// ---------------- k_mid: blocks 0-7 topk+NMS | blocks 8-15 sample+loss+final ----------------

__global__ void __launch_bounds__(1024) k_mid(
    const u32* __restrict__ kd_g, const u32* __restrict__ mant_g,
    const int* __restrict__ labels, const int* __restrict__ argmax_b,
    const int* __restrict__ gt_best, const float* __restrict__ pred,
    const float* __restrict__ cls, const float* __restrict__ gt,
    float* __restrict__ out, double* __restrict__ acc,
    int* __restrict__ cnt_out, u32* __restrict__ done)
{
    int tid = threadIdx.x;
    int lane = tid & 63, wid = tid >> 6;

    __shared__ u32 histA[4096];     // topk hist / sample hist (2048 used)
    __shared__ u64 poolB[2048];     // topk boundary buf, then (x1,y1) | sample: bitmap + sred
    __shared__ u64 sk[2048];        // topk keys/sort, then (x2,y2)
    __shared__ float4 accb[POST];   // NMS accepted boxes
    __shared__ u64 Smat[64];
    __shared__ u64 wsup[16];
    __shared__ u32 s_out[2];
    __shared__ u32 s_cnt;
    __shared__ int s_scount;
    if (tid < 2) s_out[tid] = 0;

    if (blockIdx.x < BN) {
        // ================== TOPK + NMS (batch b) ==================
        int b = blockIdx.x;
        const u32* kb = kd_g + (size_t)b * N_ANCH;

        // ---- 2-level radix select of 2000th-smallest 47-bit key ----
        u64 prefix = 0; u32 remaining = PRE; int bufcnt = -1;
        for (int p = 0; p < 4; ++p) {
            int sh = (p < 3) ? (35 - 12 * p) : 0;
            int bitsp = (p < 3) ? 12 : 11;
            int nb = 1 << bitsp;
            for (int i = tid; i < nb; i += 1024) histA[i] = 0;
            __syncthreads();
            u64 himask = ~((1ull << (sh + bitsp)) - 1);
            if (bufcnt < 0) {
                #pragma unroll
                for (int c = 0; c < 22; ++c) {
                    int n = tid + c * 1024;
                    if (n < N_ANCH) {
                        u64 kk = (((u64)kb[n]) << 15) | (u32)n;
                        if ((kk & himask) == prefix)
                            atomicAdd(&histA[(u32)((kk >> sh) & (u64)(nb - 1))], 1u);
                    }
                }
            } else {
                for (int i = tid; i < bufcnt; i += 1024) {
                    u64 kk = poolB[i];
                    if ((kk & himask) == prefix)
                        atomicAdd(&histA[(u32)((kk >> sh) & (u64)(nb - 1))], 1u);
                }
            }
            __syncthreads();
            hist_pick(histA, nb, remaining, s_out);
            u32 dig = s_out[0]; remaining = s_out[1];
            u32 bincnt = histA[dig];
            prefix |= ((u64)dig) << sh;
            __syncthreads();
            if (bufcnt < 0 && p < 3 && bincnt <= SELCAP) {
                if (tid == 0) s_cnt = 0;
                __syncthreads();
                u64 pmask = ~((1ull << sh) - 1);
                #pragma unroll
                for (int c = 0; c < 22; ++c) {
                    int n = tid + c * 1024;
                    if (n < N_ANCH) {
                        u64 kk = (((u64)kb[n]) << 15) | (u32)n;
                        if ((kk & pmask) == prefix) { u32 pos = atomicAdd(&s_cnt, 1u); poolB[pos] = kk; }
                    }
                }
                __syncthreads();
                bufcnt = (int)s_cnt;
            }
        }
        u64 T = prefix;   // exact: {key <= T} has size 2000

        // compact selected keys, bitonic sort 2048 in LDS
        if (tid == 0) s_cnt = 0;
        for (int i = tid; i < 2048; i += 1024) sk[i] = ~0ull;
        __syncthreads();
        #pragma unroll
        for (int c = 0; c < 22; ++c) {
            int n = tid + c * 1024;
            if (n < N_ANCH) {
                u64 kk = (((u64)kb[n]) << 15) | (u32)n;
                if (kk <= T) { u32 pp = atomicAdd(&s_cnt, 1u); sk[pp] = kk; }
            }
        }
        __syncthreads();
        for (int k = 2; k <= 2048; k <<= 1) {
            for (int j = k >> 1; j > 0; j >>= 1) {
                for (int i = tid; i < 2048; i += 1024) {
                    int l = i ^ j;
                    if (l > i) {
                        u64 ai = sk[i], al = sk[l];
                        bool up = ((i & k) == 0);
                        if ((ai > al) == up) { sk[i] = al; sk[l] = ai; }
                    }
                }
                __syncthreads();
            }
        }

        // recompute proposal boxes for the sorted 2000 (bit-identical math):
        // (x1,y1) -> poolB[i] as float2, (x2,y2) -> sk[i] as float2 (key read first)
        float2* bl = (float2*)poolB;
        float2* bh = (float2*)sk;
        for (int i = tid; i < 2048; i += 1024) {
            float2 lo = make_float2(0.f, 0.f), hi = make_float2(0.f, 0.f);
            if (i < PRE) {
                int n = (int)(sk[i] & 0x7fffu);
                float ax1, ay1, ax2, ay2; anchor_corners(n, ax1, ay1, ax2, ay2);
                float acx = (ax1 + ax2) * 0.5f, acy = (ay1 + ay2) * 0.5f;
                float aw = ax2 - ax1, ah = ay2 - ay1;
                int a = n % NA_T, hw = n / NA_T;
                const float* pb = pred + (size_t)b * 36 * NPOS;
                float dx = pb[(4 * a + 0) * NPOS + hw];
                float dy = pb[(4 * a + 1) * NPOS + hw];
                float dw = pb[(4 * a + 2) * NPOS + hw];
                float dh = pb[(4 * a + 3) * NPOS + hw];
                float px = acx + dx * aw, py = acy + dy * ah;
                float pw = aw * expf(dw), ph = ah * expf(dh);
                float x1 = px - 0.5f * pw, y1 = py - 0.5f * ph;
                float x2 = px + 0.5f * pw, y2 = py + 0.5f * ph;
                x1 = fminf(fmaxf(x1, 0.0f), 799.0f);
                y1 = fminf(fmaxf(y1, 0.0f), 799.0f);
                x2 = fminf(fmaxf(x2, 0.0f), 799.0f);
                y2 = fminf(fmaxf(y2, 0.0f), 799.0f);
                lo = make_float2(x1, y1); hi = make_float2(x2, y2);
            }
            bl[i] = lo; bh[i] = hi;
        }
        if (tid == 0) s_scount = 0;
        __syncthreads();

        // ---- on-the-fly greedy NMS ----
        for (int c = 0; c < 32; ++c) {
            int A = s_scount;
            int base = c * 64;
            float2 clo = bl[base + lane], chi = bh[base + lane];
            // 1) suppressed-by-accepted: 16 waves split the accepted list
            bool sup = false;
            for (int a = wid; a < A; a += 16) {
                float4 ab = accb[a];
                sup |= iou_f(ab.x, ab.y, ab.z, ab.w, clo.x, clo.y, chi.x, chi.y) > 0.7f;
            }
            u64 bal = __ballot(sup);
            if (lane == 0) wsup[wid] = bal;
            // 2) intra-chunk 64x64 suppression matrix
            #pragma unroll
            for (int q = 0; q < 4; ++q) {
                int o = wid * 4 + q;
                float2 olo = bl[base + o], ohi = bh[base + o];
                bool hit = iou_f(olo.x, olo.y, ohi.x, ohi.y, clo.x, clo.y, chi.x, chi.y) > 0.7f;
                u64 m = __ballot(hit);
                if (lane == 0) Smat[o] = m;
            }
            __syncthreads();
            // 3) wave-0 bit-ops scan
            if (wid == 0) {
                u64 supmask = 0;
                #pragma unroll
                for (int i2 = 0; i2 < 16; ++i2) supmask |= wsup[i2];
                int jmax = min(64, PRE - base);
                u64 valid = (jmax >= 64) ? ~0ull : ((1ull << jmax) - 1ull);
                u64 live = (~supmask) & valid;
                int count = A;
                while (live && count < POST) {
                    int i = __ffsll((long long)live) - 1;
                    if (lane == 0) {
                        float2 lo2 = bl[base + i], hi2 = bh[base + i];
                        accb[count] = make_float4(lo2.x, lo2.y, hi2.x, hi2.y);
                    }
                    u64 sm = Smat[i];
                    live &= ~sm;
                    live &= ~(1ull << i);
                    count++;
                }
                if (lane == 0) s_scount = count;
            }
            __syncthreads();
            if (s_scount >= POST) break;
        }
        int cntk = s_scount;
        for (int s = tid; s < POST; s += 1024) {
            float4 v = make_float4(0.f, 0.f, 0.f, 0.f);
            if (s < cntk) {
                float4 p = accb[s];
                v = make_float4(floorf(p.x), floorf(p.y), floorf(p.z), floorf(p.w));
            }
            ((float4*)out)[(size_t)b * POST + s] = v;
        }
    } else {
        // ================== SAMPLE + LOSS (batch b) ==================
        int b = blockIdx.x - BN;
        u32* bitmap = (u32*)poolB;        // 704 u32 = 2816 B
        u64* sred   = poolB + 512;        // byte offset 4096, clear of bitmap
        u32* hist   = histA;              // 2048 bins used

        for (int i = tid; i < 704; i += 1024) bitmap[i] = 0;
        __syncthreads();
        if (tid < NG) {
            int gn = gt_best[b * NG + tid];
            atomicOr(&bitmap[gn >> 5], 1u << (gn & 31));
        }
        __syncthreads();

        const int* lb = labels + (size_t)b * N_ANCH;
        const u32* mg = mant_g + (size_t)b * N_ANCH;

        u32 cp = 0, cn = 0;
        #pragma unroll
        for (int c = 0; c < 22; ++c) {
            int n = tid + c * 1024;
            if (n < N_ANCH) {
                int enc = lb[n];
                int l = (enc == -2) ? -1 : (((bitmap[n >> 5] >> (n & 31)) & 1u) ? 1 : enc);
                cp += (l == 1); cn += (l == 0);
            }
        }
        __syncthreads();
        u64 packed = block_sum_u64(((u64)cp << 32) | (u64)cn, sred, 16);
        int cpt = (int)(packed >> 32), ctot = (int)(packed & 0xffffffffu);
        int np = min(cpt, 128), nn = min(ctot, 256 - np);

        // radix select thresholds over 38-bit keys (mant<<15)|n: digits 11,9,9,9
        u64 Tp = ~0ull, Tn = ~0ull;
        for (int which = 0; which < 2; ++which) {
            bool need = which ? (ctot > nn) : (cpt > np);
            if (!need) continue;   // block-uniform
            int wl = which ? 0 : 1;
            u32 rem = which ? (u32)nn : (u32)np;
            u64 pref = 0;
            for (int p = 0; p < 4; ++p) {
                int sh = (p == 0) ? 27 : (27 - 9 * p);   // 27,18,9,0
                int bitsp = (p == 0) ? 11 : 9;
                int nb = 1 << bitsp;
                for (int i = tid; i < nb; i += 1024) hist[i] = 0;
                __syncthreads();
                u64 himask = ~((1ull << (sh + bitsp)) - 1);
                #pragma unroll
                for (int c = 0; c < 22; ++c) {
                    int n = tid + c * 1024;
                    if (n < N_ANCH) {
                        int enc = lb[n];
                        int l = (enc == -2) ? -1 : (((bitmap[n >> 5] >> (n & 31)) & 1u) ? 1 : enc);
                        if (l == wl) {
                            u64 kk = (((u64)mg[n]) << 15) | (u32)n;
                            if ((kk & himask) == pref)
                                atomicAdd(&hist[(u32)((kk >> sh) & (u64)(nb - 1))], 1u);
                        }
                    }
                }
                __syncthreads();
                hist_pick(hist, nb, rem, s_out);
                pref |= ((u64)s_out[0]) << sh;
                rem = s_out[1];
                __syncthreads();
            }
            if (which == 0) Tp = pref; else Tn = pref;
        }

        // loss over selected samples
        double lcls = 0.0, lbox = 0.0;
        #pragma unroll
        for (int c = 0; c < 22; ++c) {
            int n = tid + c * 1024;
            if (n >= N_ANCH) continue;
            int enc = lb[n];
            int l = (enc == -2) ? -1 : (((bitmap[n >> 5] >> (n & 31)) & 1u) ? 1 : enc);
            if (l < 0) continue;
            u64 kk = (((u64)mg[n]) << 15) | (u32)n;
            int lab = -1;
            if (l == 1) { if (kk <= Tp) lab = 1; }
            else        { if (kk <= Tn) lab = 0; }
            if (lab < 0) continue;
            int a = n % NA_T, hw = n / NA_T;
            float l0 = cls[((size_t)b * 18 + 2 * a + 0) * NPOS + hw];
            float l1 = cls[((size_t)b * 18 + 2 * a + 1) * NPOS + hw];
            float m = fmaxf(l0, l1);
            float s0 = l0 - m, s1 = l1 - m;
            float lse = logf(expf(s0) + expf(s1));
            lcls += (double)(-((lab ? s1 : s0) - lse));
            if (lab == 1) {
                const float* pb = pred + (size_t)b * 36 * NPOS;
                float dx = pb[(4 * a + 0) * NPOS + hw];
                float dy = pb[(4 * a + 1) * NPOS + hw];
                float dw = pb[(4 * a + 2) * NPOS + hw];
                float dh = pb[(4 * a + 3) * NPOS + hw];
                float ax1, ay1, ax2, ay2; anchor_corners(n, ax1, ay1, ax2, ay2);
                float acx = (ax1 + ax2) * 0.5f, acy = (ay1 + ay2) * 0.5f;
                float aw = ax2 - ax1, ah = ay2 - ay1;
                float4 G = ((const float4*)gt)[b * NG + argmax_b[(size_t)b * N_ANCH + n]];
                float gcx = (G.x + G.z) * 0.5f, gcy = (G.y + G.w) * 0.5f;
                float gw = G.z - G.x, gh = G.w - G.y;
                float t0 = (gcx - acx) / aw, t1 = (gcy - acy) / ah;
                float t2 = logf(gw / aw), t3 = logf(gh / ah);
                lbox += (double)(smooth_l1(dx - t0) + smooth_l1(dy - t1) +
                                 smooth_l1(dw - t2) + smooth_l1(dh - t3));
            }
        }
        for (int o = 32; o >= 1; o >>= 1) {
            lcls += __shfl_down(lcls, o);
            lbox += __shfl_down(lbox, o);
        }
        if ((tid & 63) == 0) {
            atomicAdd(&acc[0], lcls);
            atomicAdd(&acc[1], lbox);
        }
        if (tid == 0) cnt_out[b] = np + nn;
        __syncthreads();

        // last sample block writes the two losses
        if (tid == 0) {
            __threadfence();
            u32 r = atomicAdd(done, 1u);
            if (r == BN - 1) {
                __threadfence();
                volatile double* va = (volatile double*)acc;
                volatile int* vc = (volatile int*)cnt_out;
                double a0 = va[0], a1 = va[1];
                int total = 0, c0 = 0;
                for (int bb = 0; bb < BN; ++bb) {
                    int v = vc[bb];
                    total += v;
                    if (bb == 0) c0 = v;
                }
                out[BN * POST * 4 + 0] = (float)(a1 / (double)max(c0, 1));     // bbox_loss
                out[BN * POST * 4 + 1] = (float)(a0 / (double)max(total, 1));  // cls_loss
            }
        }
    }
}

// ---------------- launch ----------------

extern "C" void kernel_launch(void* const* d_in, const int* in_sizes, int n_in,
                              void* d_out, int out_size, void* d_ws, size_t ws_size,
                              hipStream_t stream) {
    (void)in_sizes; (void)n_in; (void)out_size; (void)ws_size;
    const float* pred = (const float*)d_in[0];   // (8,36,50,50)
    const float* cls  = (const float*)d_in[1];   // (8,18,50,50)
    const float* gt   = (const float*)d_in[2];   // (8,20,4)
    float* out = (float*)d_out;                  // 9600 boxes + 2 losses

    char* w = (char*)d_ws;
    size_t off = 0;
    auto take = [&](size_t bytes) { void* p = w + off; off += (bytes + 255) & ~(size_t)255; return p; };
    u32* kd_g    = (u32*)take((size_t)TOTAL * 4);          // 720 KB
    u32* mant_g  = (u32*)take((size_t)TOTAL * 4);          // 720 KB
    int* labels  = (int*)take((size_t)TOTAL * 4);          // 720 KB
    int* argmax_b= (int*)take((size_t)TOTAL * 4);          // 720 KB
    int* gt_best = (int*)take((size_t)BN * NG * 4);
    int* cnt_out = (int*)take(BN * 4);
    double* acc  = (double*)take(2 * 8);
    u32* done    = (u32*)take(4);

    k_front<<<NB_PROP + NB_LAB + NB_GTB, 256, 0, stream>>>(cls, gt, kd_g, mant_g,
                                                           labels, argmax_b, gt_best,
                                                           acc, done);
    k_mid<<<2 * BN, 1024, 0, stream>>>(kd_g, mant_g, labels, argmax_b, gt_best,
                                       pred, cls, gt, out, acc, cnt_out, done);
}